// Round 1
// 566.140 us; speedup vs baseline: 1.4168x; 1.4168x over previous
//
#include <hip/hip_runtime.h>
#include <math.h>

#define BS   2048
#define SEQ  50
#define NPOS (BS * SEQ)

typedef __attribute__((ext_vector_type(8))) short bf16x8;   // 8 bf16 = 4 VGPR
typedef __attribute__((ext_vector_type(4))) float f32x4;

__device__ __forceinline__ float sigf(float x) { return 1.0f / (1.0f + __expf(-x)); }
__device__ __forceinline__ float tanhfast(float x) {
    float e = __expf(2.0f * x);
    return 1.0f - 2.0f / (e + 1.0f);
}
__device__ __forceinline__ unsigned short bfrn(float x) {   // fp32 -> bf16 rne
    unsigned int u = __float_as_uint(x);
    u += 0x7FFFu + ((u >> 16) & 1u);
    return (unsigned short)(u >> 16);
}
__device__ __forceinline__ float bf2f(unsigned short h) {
    return __uint_as_float(((unsigned int)h) << 16);
}

// ---- macro toolkit for kernel A (unchanged) -------------------------------
#define FMA4(A, X, W) \
    A = fmaf((X).x, (W).x, A); A = fmaf((X).y, (W).y, A); \
    A = fmaf((X).z, (W).z, A); A = fmaf((X).w, (W).w, A);

#define LD16(P, N) \
    float4 N##0=(P)[0],  N##1=(P)[1],  N##2=(P)[2],  N##3=(P)[3], \
           N##4=(P)[4],  N##5=(P)[5],  N##6=(P)[6],  N##7=(P)[7], \
           N##8=(P)[8],  N##9=(P)[9],  N##10=(P)[10],N##11=(P)[11], \
           N##12=(P)[12],N##13=(P)[13],N##14=(P)[14],N##15=(P)[15];

// ---------------------------------------------------------------------------
// prep_frags: build MFMA B-operand fragments (bf16 hi/lo split) for W_hh and
// W_ih. B-frag layout for mfma_f32_16x16x32_bf16: lane l holds n = tile*16 +
// (l&15), k = kc*32 + (l>>4)*8 + j  (j = 0..7 contiguous shorts).
//   whF[frag*64 + l], frag = w*32 + ti*8 + kc*2 + p   (tile = w + 8*ti)
//   wiF[frag*64 + l], frag = tile*4 + kc*2 + p
// p=0: bf16_rn(x) ("hi");  p=1: bf16_rn(x - hi) ("lo").
// ---------------------------------------------------------------------------
__global__ __launch_bounds__(512) void prep_frags(
    const float* __restrict__ Wih, const float* __restrict__ Whh,
    bf16x8* __restrict__ whF, bf16x8* __restrict__ wiF)
{
    int id = blockIdx.x * 512 + threadIdx.x;   // grid covers 24576 exactly
    const float* src;
    bf16x8* dst;
    int p;
    if (id < 16384) {
        int l = id & 63, frag = id >> 6;        // 0..255
        p = frag & 1;
        int kc = (frag >> 1) & 3, ti = (frag >> 3) & 3, w = frag >> 5;
        int n  = (w + 8 * ti) * 16 + (l & 15);
        int k0 = kc * 32 + (l >> 4) * 8;
        src = &Whh[n * 128 + k0];
        dst = &whF[frag * 64 + l];
    } else {
        int id2 = id - 16384;
        int l = id2 & 63, frag = id2 >> 6;      // 0..127
        p = frag & 1;
        int kc = (frag >> 1) & 1, tile = frag >> 2;
        int n  = tile * 16 + (l & 15);
        int k0 = kc * 32 + (l >> 4) * 8;
        src = &Wih[n * 64 + k0];
        dst = &wiF[frag * 64 + l];
    }
    bf16x8 v;
    #pragma unroll
    for (int j = 0; j < 8; ++j) {
        float x = src[j];
        unsigned short hi = bfrn(x);
        unsigned short r  = p ? bfrn(x - bf2f(hi)) : hi;
        v[j] = (short)r;
    }
    *dst = v;
}

// ---------------------------------------------------------------------------
// Kernel A: unchanged (~320 us; not the target this round).
// ---------------------------------------------------------------------------
__global__
__attribute__((amdgpu_flat_work_group_size(64, 64), amdgpu_waves_per_eu(2, 2)))
void edge_attn_ctx(
    const float* __restrict__ seqs,   // [BS,SEQ,3,3,6]
    const float* __restrict__ ets,    // [BS,SEQ,3,3,4]
    const int*   __restrict__ masks,  // [BS,SEQ,3,3]
    const float* __restrict__ Wf, const float* __restrict__ bf,
    const float* __restrict__ Wk, const float* __restrict__ bk,
    const float* __restrict__ Wq, const float* __restrict__ bq,
    const float* __restrict__ Wv, const float* __restrict__ bv,
    float* __restrict__ ctx)          // [BS,SEQ,64]
{
    const int o = threadIdx.x;

    const float4* qp = (const float4*)&Wq[o * 64];
    LD16(qp, wq)
    const float4* vp = (const float4*)&Wv[o * 64];
    LD16(vp, wv)

    const float* wfp = &Wf[o * 19];
    float wf0=wfp[0], wf1=wfp[1], wf2=wfp[2], wf3=wfp[3], wf4=wfp[4], wf5=wfp[5],
          wf6=wfp[6], wf7=wfp[7], wf8=wfp[8], wf9=wfp[9];
    float wfe0=wfp[10], wfe1=wfp[11], wfe2=wfp[12], wfe3=wfp[13], wfe4=wfp[14],
          wfe5=wfp[15], wfe6=wfp[16], wfe7=wfp[17], wfe8=wfp[18];
    const float* wkp = &Wk[o * 6];
    float wk0=wkp[0], wk1=wkp[1], wk2=wkp[2], wk3=wkp[3], wk4=wkp[4], wk5=wkp[5];

    const float bfr = bf[o], bkr = bk[o], bqr = bq[o], bvr = bv[o];

    __shared__ float s_seq[54];
    __shared__ float s_et[36];
    __shared__ int   s_mask[9];
    __shared__ float s_edge[9 * 64];

    for (int p = blockIdx.x; p < NPOS; p += gridDim.x) {
        if (o < 54) s_seq[o]  = seqs[p * 54 + o];
        if (o < 36) s_et[o]   = ets[p * 36 + o];
        if (o < 9)  s_mask[o] = masks[p * 9 + o];
        __syncthreads();

        float wfe[9] = {wfe0,wfe1,wfe2,wfe3,wfe4,wfe5,wfe6,wfe7,wfe8};
        #pragma unroll
        for (int e = 0; e < 9; ++e) {
            float v = bfr + wfe[e];
            v = fmaf(s_seq[e*6+0], wf0, v);
            v = fmaf(s_seq[e*6+1], wf1, v);
            v = fmaf(s_seq[e*6+2], wf2, v);
            v = fmaf(s_seq[e*6+3], wf3, v);
            v = fmaf(s_seq[e*6+4], wf4, v);
            v = fmaf(s_seq[e*6+5], wf5, v);
            v = fmaf(s_et[e*4+0],  wf6, v);
            v = fmaf(s_et[e*4+1],  wf7, v);
            v = fmaf(s_et[e*4+2],  wf8, v);
            v = fmaf(s_et[e*4+3],  wf9, v);
            s_edge[e * 64 + o] = v;
        }
        float key = bkr;
        key = fmaf(s_seq[24], wk0, key);
        key = fmaf(s_seq[25], wk1, key);
        key = fmaf(s_seq[26], wk2, key);
        key = fmaf(s_seq[27], wk3, key);
        key = fmaf(s_seq[28], wk4, key);
        key = fmaf(s_seq[29], wk5, key);
        __syncthreads();

        float vv[9], att[9];
        #pragma unroll
        for (int e = 0; e < 9; ++e) {
            const float4* ep = (const float4*)&s_edge[e * 64];
            float q = 0.f, v = 0.f;
            {
                float4 t;
                t=ep[0];  FMA4(q,t,wq0)  FMA4(v,t,wv0)
                t=ep[1];  FMA4(q,t,wq1)  FMA4(v,t,wv1)
                t=ep[2];  FMA4(q,t,wq2)  FMA4(v,t,wv2)
                t=ep[3];  FMA4(q,t,wq3)  FMA4(v,t,wv3)
                t=ep[4];  FMA4(q,t,wq4)  FMA4(v,t,wv4)
                t=ep[5];  FMA4(q,t,wq5)  FMA4(v,t,wv5)
                t=ep[6];  FMA4(q,t,wq6)  FMA4(v,t,wv6)
                t=ep[7];  FMA4(q,t,wq7)  FMA4(v,t,wv7)
                t=ep[8];  FMA4(q,t,wq8)  FMA4(v,t,wv8)
                t=ep[9];  FMA4(q,t,wq9)  FMA4(v,t,wv9)
                t=ep[10]; FMA4(q,t,wq10) FMA4(v,t,wv10)
                t=ep[11]; FMA4(q,t,wq11) FMA4(v,t,wv11)
                t=ep[12]; FMA4(q,t,wq12) FMA4(v,t,wv12)
                t=ep[13]; FMA4(q,t,wq13) FMA4(v,t,wv13)
                t=ep[14]; FMA4(q,t,wq14) FMA4(v,t,wv14)
                t=ep[15]; FMA4(q,t,wq15) FMA4(v,t,wv15)
            }
            float qq = bqr + q;
            vv[e] = bvr + v;
            float a_ = key * qq;
            a_ += __shfl_xor(a_, 8, 16);
            a_ += __shfl_xor(a_, 4, 16);
            a_ += __shfl_xor(a_, 2, 16);
            a_ += __shfl_xor(a_, 1, 16);
            att[e] = a_ * 0.25f;   // / sqrt(16)
        }

        float mx = -3.0e38f;
        #pragma unroll
        for (int e = 0; e < 9; ++e) {
            att[e] = (s_mask[e] == 0) ? -1.0e10f : att[e];
            mx = fmaxf(mx, att[e]);
        }
        float ssum = 0.f;
        #pragma unroll
        for (int e = 0; e < 9; ++e) { att[e] = __expf(att[e] - mx); ssum += att[e]; }
        float inv = 1.f / ssum;
        float acc = 0.f;
        #pragma unroll
        for (int e = 0; e < 9; ++e) acc = fmaf(att[e], vv[e], acc);
        ctx[p * 64 + o] = acc * inv;
        __syncthreads();
    }
}

// ---------------------------------------------------------------------------
// Kernel C v9: MFMA LSTM. 128 blocks x 512 thr (8 waves), 16 batch rows/block.
// Per step: gates[16,512] = x[16,64]@WihT + h[16,128]@WhhT via 3-pass bf16
// hi/lo split (hi*hi + lo*hi + hi*lo ~ fp32).  Wave w owns N-tiles
// {w, w+8, w+16, w+24} so lane (l&15) holds i,f,g,o of hidden unit m=16w+(l&15)
// for rows (l>>4)*4+r  -> pointwise fully in-register, no shuffles.
//  - W_hh frags: 128 VGPR, loaded once (whF).
//  - W_ih frags: 128 KB LDS, re-read per step (barrier pins them in-loop).
//  - h / x staged in LDS as bf16 hi/lo with XOR swizzle byte^=(row&7)<<4 so
//    the stride-256B/128B A-frag ds_read_b128 are bank-conflict-free.
//  - 2 barriers/step: [stage x] B1 [frag reads + MFMA] B2 [pointwise, write h].
// ---------------------------------------------------------------------------
#define MFMA16(A, B, C) __builtin_amdgcn_mfma_f32_16x16x32_bf16(A, B, C, 0, 0, 0)

__global__ __launch_bounds__(512, 2) void lstm_mfma(
    const float*  __restrict__ ctx,    // [BS,SEQ,64]
    const bf16x8* __restrict__ whF,    // 16384 frags
    const bf16x8* __restrict__ wiFg,   // 8192 frags
    const float*  __restrict__ b_ih, const float* __restrict__ b_hh,
    const float*  __restrict__ W_out, const float* __restrict__ b_out,
    float* __restrict__ out)           // [BS,64]
{
    const int t  = threadIdx.x;
    const int w  = t >> 6, l = t & 63;
    const int lm = l & 15, lq = l >> 4;
    const int row0 = blockIdx.x * 16;

    __shared__ bf16x8 s_wi[8192];                       // 128 KB  W_ih frags
    __shared__ unsigned short s_xh[1024], s_xl[1024];   // [16][64]  swizzled
    __shared__ unsigned short s_hh[2048], s_hl[2048];   // [16][128] swizzled

    for (int i = t; i < 8192; i += 512) s_wi[i] = wiFg[i];

    // W_hh fragments -> registers for the whole loop (32 x 4 VGPR = 128)
    bf16x8 whr[4][4][2];
    #pragma unroll
    for (int ti = 0; ti < 4; ++ti)
        #pragma unroll
        for (int kc = 0; kc < 4; ++kc)
            #pragma unroll
            for (int p = 0; p < 2; ++p)
                whr[ti][kc][p] = whF[(((w * 4 + ti) * 4 + kc) * 2 + p) * 64 + l];

    const int m = w * 16 + lm;        // hidden unit this lane handles
    const float bi  = b_ih[m]       + b_hh[m];
    const float bff = b_ih[128 + m] + b_hh[128 + m];
    const float bg  = b_ih[256 + m] + b_hh[256 + m];
    const float bo  = b_ih[384 + m] + b_hh[384 + m];

    float c[4] = {0.f, 0.f, 0.f, 0.f};   // c-state, rows lq*4 + r

    const int xrow = t >> 5;             // staging: row 0..15
    const int xl32 = t & 31;             // col pair
    const float2* ctx2 = (const float2*)ctx;
    const int xbase = (row0 + xrow) * SEQ;
    const int xwb   = xrow * 128 + ((4 * xl32) ^ ((xrow & 7) << 4));
    const int swzr  = (lm & 7) << 4;     // read-side swizzle (row = lm)
    const int hwb_m = 32 * w + 2 * lm;   // h write byte-in-row (before swizzle)

    for (int s = 0; s < SEQ; ++s) {
        // ---- stage x (hi/lo bf16, swizzled) ----
        float2 xv = ctx2[(xbase + s) * 32 + xl32];
        unsigned short xh0 = bfrn(xv.x), xh1 = bfrn(xv.y);
        unsigned short xl0 = bfrn(xv.x - bf2f(xh0)), xl1 = bfrn(xv.y - bf2f(xh1));
        *(unsigned int*)((char*)s_xh + xwb) = (unsigned int)xh0 | ((unsigned int)xh1 << 16);
        *(unsigned int*)((char*)s_xl + xwb) = (unsigned int)xl0 | ((unsigned int)xl1 << 16);
        __syncthreads();

        // ---- A-fragment reads (conflict-free via swizzle) ----
        bf16x8 xfh[2], xfl[2];
        #pragma unroll
        for (int kc = 0; kc < 2; ++kc) {
            int b = lm * 128 + ((kc * 64 + lq * 16) ^ swzr);
            xfh[kc] = *(const bf16x8*)((const char*)s_xh + b);
            xfl[kc] = *(const bf16x8*)((const char*)s_xl + b);
        }
        bf16x8 hfh[4], hfl[4];
        if (s > 0) {
            #pragma unroll
            for (int kc = 0; kc < 4; ++kc) {
                int b = lm * 256 + ((kc * 64 + lq * 16) ^ swzr);
                hfh[kc] = *(const bf16x8*)((const char*)s_hh + b);
                hfl[kc] = *(const bf16x8*)((const char*)s_hl + b);
            }
        }

        // ---- MFMA: 4 independent acc chains (tiles w, w+8, w+16, w+24) ----
        f32x4 a0 = {0.f,0.f,0.f,0.f}, a1 = a0, a2 = a0, a3 = a0;
        #pragma unroll
        for (int kc = 0; kc < 2; ++kc) {
            bf16x8 wihi[4], wilo[4];
            #pragma unroll
            for (int ti = 0; ti < 4; ++ti) {
                int base = (((w + 8 * ti) * 2 + kc) * 2) * 64 + l;
                wihi[ti] = s_wi[base];
                wilo[ti] = s_wi[base + 64];
            }
            a0 = MFMA16(xfh[kc], wihi[0], a0); a1 = MFMA16(xfh[kc], wihi[1], a1);
            a2 = MFMA16(xfh[kc], wihi[2], a2); a3 = MFMA16(xfh[kc], wihi[3], a3);
            a0 = MFMA16(xfl[kc], wihi[0], a0); a1 = MFMA16(xfl[kc], wihi[1], a1);
            a2 = MFMA16(xfl[kc], wihi[2], a2); a3 = MFMA16(xfl[kc], wihi[3], a3);
            a0 = MFMA16(xfh[kc], wilo[0], a0); a1 = MFMA16(xfh[kc], wilo[1], a1);
            a2 = MFMA16(xfh[kc], wilo[2], a2); a3 = MFMA16(xfh[kc], wilo[3], a3);
        }
        if (s > 0) {
            #pragma unroll
            for (int kc = 0; kc < 4; ++kc) {
                a0 = MFMA16(hfh[kc], whr[0][kc][0], a0); a1 = MFMA16(hfh[kc], whr[1][kc][0], a1);
                a2 = MFMA16(hfh[kc], whr[2][kc][0], a2); a3 = MFMA16(hfh[kc], whr[3][kc][0], a3);
                a0 = MFMA16(hfl[kc], whr[0][kc][0], a0); a1 = MFMA16(hfl[kc], whr[1][kc][0], a1);
                a2 = MFMA16(hfl[kc], whr[2][kc][0], a2); a3 = MFMA16(hfl[kc], whr[3][kc][0], a3);
                a0 = MFMA16(hfh[kc], whr[0][kc][1], a0); a1 = MFMA16(hfh[kc], whr[1][kc][1], a1);
                a2 = MFMA16(hfh[kc], whr[2][kc][1], a2); a3 = MFMA16(hfh[kc], whr[3][kc][1], a3);
            }
        }
        __syncthreads();   // all LDS reads done before h overwrite

        // ---- pointwise (in-register: lane has i,f,g,o of unit m, 4 rows) ----
        #pragma unroll
        for (int r = 0; r < 4; ++r) {
            float ig = sigf(a0[r] + bi);
            float fg = sigf(a1[r] + bff);
            float gt = tanhfast(a2[r] + bg);
            float og = sigf(a3[r] + bo);
            c[r] = fmaf(fg, c[r], ig * gt);
            float h = og * tanhfast(c[r]);
            unsigned short hh_ = bfrn(h);
            unsigned short hl_ = bfrn(h - bf2f(hh_));
            int row = lq * 4 + r;
            int b = row * 256 + (hwb_m ^ ((row & 7) << 4));
            *(unsigned short*)((char*)s_hh + b) = hh_;
            *(unsigned short*)((char*)s_hl + b) = hl_;
        }
    }
    __syncthreads();

    // ---- epilogue: out[row][j] = b_out[j] + h[row] . W_out[j] ----
    {
        const int row = t >> 5;
        const int j0 = t & 31, j1 = (t & 31) + 32;
        const int rswz = (row & 7) << 4;
        float accA = b_out[j0], accB = b_out[j1];
        #pragma unroll
        for (int kq = 0; kq < 16; ++kq) {
            int b = row * 256 + ((kq * 16) ^ rswz);
            bf16x8 hh8 = *(const bf16x8*)((const char*)s_hh + b);
            bf16x8 hl8 = *(const bf16x8*)((const char*)s_hl + b);
            #pragma unroll
            for (int e = 0; e < 8; ++e) {
                float h = bf2f((unsigned short)hh8[e]) + bf2f((unsigned short)hl8[e]);
                int k = kq * 8 + e;
                accA = fmaf(h, W_out[j0 * 128 + k], accA);
                accB = fmaf(h, W_out[j1 * 128 + k], accB);
            }
        }
        out[(row0 + row) * 64 + j0] = accA;
        out[(row0 + row) * 64 + j1] = accB;
    }
}

// ---------------------------------------------------------------------------
extern "C" void kernel_launch(void* const* d_in, const int* in_sizes, int n_in,
                              void* d_out, int out_size, void* d_ws, size_t ws_size,
                              hipStream_t stream) {
    (void)in_sizes; (void)n_in; (void)out_size; (void)ws_size;
    const float* seqs  = (const float*)d_in[0];
    const float* ets   = (const float*)d_in[1];
    const int*   masks = (const int*)d_in[2];
    const float* Wf  = (const float*)d_in[3];
    const float* bf  = (const float*)d_in[4];
    const float* Wk  = (const float*)d_in[5];
    const float* bk  = (const float*)d_in[6];
    const float* Wq  = (const float*)d_in[7];
    const float* bq  = (const float*)d_in[8];
    const float* Wv  = (const float*)d_in[9];
    const float* bv  = (const float*)d_in[10];
    const float* Wih = (const float*)d_in[11];
    const float* Whh = (const float*)d_in[12];
    const float* bih = (const float*)d_in[13];
    const float* bhh = (const float*)d_in[14];
    const float* Wo  = (const float*)d_in[15];
    const float* bo  = (const float*)d_in[16];

    // ws layout: whF 256K | wiF 128K | ctx 26.2M   (same 26,607,616 B total)
    char* ws = (char*)d_ws;
    bf16x8* whF = (bf16x8*)(ws);
    bf16x8* wiF = (bf16x8*)(ws + 262144);
    float*  ctx = (float*) (ws + 262144 + 131072);

    hipLaunchKernelGGL(prep_frags, dim3(48), dim3(512), 0, stream,
                       Wih, Whh, whF, wiF);
    hipLaunchKernelGGL(edge_attn_ctx, dim3(4096), dim3(64), 0, stream,
                       seqs, ets, masks, Wf, bf, Wk, bk, Wq, bq, Wv, bv, ctx);
    hipLaunchKernelGGL(lstm_mfma, dim3(128), dim3(512), 0, stream,
                       ctx, whF, wiF, bih, bhh, Wo, bo, (float*)d_out);
}

// Round 2
// 311.779 us; speedup vs baseline: 2.5727x; 1.8158x over previous
//
#include <hip/hip_runtime.h>
#include <math.h>

#define BS   2048
#define SEQ  50
#define NPOS (BS * SEQ)

typedef __attribute__((ext_vector_type(8))) short bf16x8;   // 8 bf16 = 4 VGPR
typedef __attribute__((ext_vector_type(4))) float f32x4;

__device__ __forceinline__ float sigf(float x) { return 1.0f / (1.0f + __expf(-x)); }
__device__ __forceinline__ float tanhfast(float x) {
    float e = __expf(2.0f * x);
    return 1.0f - 2.0f / (e + 1.0f);
}
__device__ __forceinline__ unsigned short bfrn(float x) {   // fp32 -> bf16 rne
    unsigned int u = __float_as_uint(x);
    u += 0x7FFFu + ((u >> 16) & 1u);
    return (unsigned short)(u >> 16);
}
__device__ __forceinline__ float bf2f(unsigned short h) {
    return __uint_as_float(((unsigned int)h) << 16);
}

#define FMA4(A, X, W) \
    A = fmaf((X).x, (W).x, A); A = fmaf((X).y, (W).y, A); \
    A = fmaf((X).z, (W).z, A); A = fmaf((X).w, (W).w, A);

// ---------------------------------------------------------------------------
// Precomputed attention tables (position-independent, built by prep kernel):
//   G  [64][10]: G[n][k]  = sum_j Wq[n][j] * Wf[j][k]            (k = raw10 col)
//   D  [9][64]:  D[e][n]  = sum_j (Wf[j][10+e]+bf[j]) * Wq[n][j] + bq[n]
//   Wvf[64][10]: Wvf[o][k]= sum_j Wv[o][j] * Wf[j][k]
//   Ce [64][9]:  Ce[o][e] = sum_j (Wf[j][10+e]+bf[j]) * Wv[o][j]
// Then per position:
//   key[d] = self6 . Wk[d] + bk[d]
//   g_h[k] = sum_d key[h16+d] G[h16+d][k]
//   att[e][h] = 0.25*(raw10_e . g_h + sum_d key[h16+d] D[e][h16+d]),  mask
//   p = softmax_e(att)
//   rbar_h[k] = sum_e p[e][h] raw10_e[k]
//   ctx[o] = rbar_h(o) . Wvf[o] + sum_e p[e][h(o)] (Ce[o][e]+bv[o])
// ---------------------------------------------------------------------------
__device__ float G_d[640];
__device__ float D_d[576];
__device__ float Wvf_d[640];
__device__ float Ce_d[576];

// ---------------------------------------------------------------------------
// prep: blocks 0..47 build MFMA weight fragments (unchanged logic);
//       blocks 48..52 build the attention tables above.
// ---------------------------------------------------------------------------
__global__ __launch_bounds__(512) void prep_all(
    const float* __restrict__ Wih, const float* __restrict__ Whh,
    bf16x8* __restrict__ whF, bf16x8* __restrict__ wiF,
    const float* __restrict__ Wf, const float* __restrict__ bf,
    const float* __restrict__ Wq, const float* __restrict__ bq,
    const float* __restrict__ Wv)
{
    int id = blockIdx.x * 512 + threadIdx.x;
    if (id < 24576) {
        const float* src;
        bf16x8* dst;
        int p;
        if (id < 16384) {
            int l = id & 63, frag = id >> 6;        // 0..255
            p = frag & 1;
            int kc = (frag >> 1) & 3, ti = (frag >> 3) & 3, w = frag >> 5;
            int n  = (w + 8 * ti) * 16 + (l & 15);
            int k0 = kc * 32 + (l >> 4) * 8;
            src = &Whh[n * 128 + k0];
            dst = &whF[frag * 64 + l];
        } else {
            int id2 = id - 16384;
            int l = id2 & 63, frag = id2 >> 6;      // 0..127
            p = frag & 1;
            int kc = (frag >> 1) & 1, tile = frag >> 2;
            int n  = tile * 16 + (l & 15);
            int k0 = kc * 32 + (l >> 4) * 8;
            src = &Wih[n * 64 + k0];
            dst = &wiF[frag * 64 + l];
        }
        bf16x8 v;
        #pragma unroll
        for (int j = 0; j < 8; ++j) {
            float x = src[j];
            unsigned short hi = bfrn(x);
            unsigned short r  = p ? bfrn(x - bf2f(hi)) : hi;
            v[j] = (short)r;
        }
        *dst = v;
        return;
    }
    int i = id - 24576;
    if (i >= 2432) return;
    if (i < 640) {                       // G[n][k]
        int n = i / 10, k = i % 10;
        float s = 0.f;
        #pragma unroll 8
        for (int j = 0; j < 64; ++j) s = fmaf(Wq[n * 64 + j], Wf[j * 19 + k], s);
        G_d[i] = s;
    } else if (i < 1216) {               // D[e][n]
        int i2 = i - 640;
        int e = i2 >> 6, n = i2 & 63;
        float s = bq[n];
        #pragma unroll 8
        for (int j = 0; j < 64; ++j)
            s = fmaf(Wf[j * 19 + 10 + e] + bf[j], Wq[n * 64 + j], s);
        D_d[i2] = s;
    } else if (i < 1856) {               // Wvf[o][k]
        int i3 = i - 1216;
        int o = i3 / 10, k = i3 % 10;
        float s = 0.f;
        #pragma unroll 8
        for (int j = 0; j < 64; ++j) s = fmaf(Wv[o * 64 + j], Wf[j * 19 + k], s);
        Wvf_d[i3] = s;
    } else {                             // Ce[o][e]
        int i4 = i - 1856;
        int o = i4 / 9, e = i4 % 9;
        float s = 0.f;
        #pragma unroll 8
        for (int j = 0; j < 64; ++j)
            s = fmaf(Wf[j * 19 + 10 + e] + bf[j], Wv[o * 64 + j], s);
        Ce_d[i4] = s;
    }
}

// ---------------------------------------------------------------------------
// Kernel A v2: algebraically-collapsed attention. 1 wave/block, 4096 blocks
// (= 16 WGs/CU), grid-stride 25 positions each. ~4.5K FMA/position (was 82K).
// 6 barriers/position; next-position global loads issued 5 barriers early.
// ---------------------------------------------------------------------------
__global__ __launch_bounds__(64, 4) void edge_attn_ctx(
    const float* __restrict__ seqs,   // [BS,SEQ,3,3,6]
    const float* __restrict__ ets,    // [BS,SEQ,3,3,4]
    const int*   __restrict__ masks,  // [BS,SEQ,3,3]
    const float* __restrict__ Wk, const float* __restrict__ bk,
    const float* __restrict__ bv,
    float* __restrict__ ctx)          // [BS,SEQ,64]
{
    const int o   = threadIdx.x;
    const int h_o = o >> 4;
    const int lg  = (o < 40) ? o : 0;     // g/rbar lanes: (gh, gk)
    const int gh  = lg / 10, gk = lg % 10;
    const int la  = (o < 36) ? o : 0;     // att lanes: (ah, ae), l = ah*9+ae
    const int ah  = la / 9,  ae = la % 9;

    // loop-invariant register tables
    const float* wkp = &Wk[o * 6];
    const float wk0 = wkp[0], wk1 = wkp[1], wk2 = wkp[2],
                wk3 = wkp[3], wk4 = wkp[4], wk5 = wkp[5];
    const float bkr = bk[o];

    float Greg[16], Dreg[16];
    #pragma unroll
    for (int d = 0; d < 16; ++d) Greg[d] = G_d[(gh * 16 + d) * 10 + gk];
    #pragma unroll
    for (int d = 0; d < 16; ++d) Dreg[d] = D_d[ae * 64 + ah * 16 + d];
    float Wvfr[10];
    #pragma unroll
    for (int k = 0; k < 10; ++k) Wvfr[k] = Wvf_d[o * 10 + k];
    const float bvr = bv[o];
    float Cer[9];
    #pragma unroll
    for (int e = 0; e < 9; ++e) Cer[e] = Ce_d[o * 9 + e] + bvr;

    __shared__ float s_seq[54], s_et[36], s_key[64], s_g[40];
    __shared__ float s_att[36], s_exp[36], s_rbar[40];
    __shared__ int   s_mask[9];

    // prefetch position blockIdx.x
    float r_seq = 0.f, r_et = 0.f; int r_mask = 0;
    {
        int p0 = blockIdx.x;
        if (o < 54) r_seq  = seqs[p0 * 54 + o];
        if (o < 36) r_et   = ets[p0 * 36 + o];
        if (o < 9)  r_mask = masks[p0 * 9 + o];
    }

    for (int p = blockIdx.x; p < NPOS; p += gridDim.x) {
        // ---- stage (from prefetched regs) ----
        if (o < 54) s_seq[o]  = r_seq;
        if (o < 36) s_et[o]   = r_et;
        if (o < 9)  s_mask[o] = r_mask;
        __syncthreads();

        // ---- key + issue next-position prefetch (latency spans 5 barriers) --
        {
            int pn = p + gridDim.x;
            if (pn < NPOS) {
                if (o < 54) r_seq  = seqs[pn * 54 + o];
                if (o < 36) r_et   = ets[pn * 36 + o];
                if (o < 9)  r_mask = masks[pn * 9 + o];
            }
        }
        float key = bkr;
        key = fmaf(s_seq[24], wk0, key);
        key = fmaf(s_seq[25], wk1, key);
        key = fmaf(s_seq[26], wk2, key);
        key = fmaf(s_seq[27], wk3, key);
        key = fmaf(s_seq[28], wk4, key);
        key = fmaf(s_seq[29], wk5, key);
        s_key[o] = key;
        __syncthreads();

        // ---- g_h[k] (lanes<40) and D-term (lanes<36) ----
        float tt = 0.f;
        if (o < 40) {
            float g = 0.f;
            #pragma unroll
            for (int d = 0; d < 16; ++d) g = fmaf(Greg[d], s_key[gh * 16 + d], g);
            s_g[o] = g;
        }
        if (o < 36) {
            #pragma unroll
            for (int d = 0; d < 16; ++d) tt = fmaf(Dreg[d], s_key[ah * 16 + d], tt);
        }
        __syncthreads();

        // ---- att[e][h] (lanes<36) ----
        float a = 0.f;
        if (o < 36) {
            a = tt;
            #pragma unroll
            for (int k = 0; k < 6; ++k) a = fmaf(s_seq[ae * 6 + k], s_g[ah * 10 + k], a);
            #pragma unroll
            for (int k = 0; k < 4; ++k) a = fmaf(s_et[ae * 4 + k], s_g[ah * 10 + 6 + k], a);
            a *= 0.25f;
            if (s_mask[ae] == 0) a = -1.0e10f;
            s_att[o] = a;
        }
        __syncthreads();

        // ---- exp with per-head max (lanes<36) ----
        float ex = 0.f;
        if (o < 36) {
            float mx = s_att[ah * 9 + 0];
            #pragma unroll
            for (int e = 1; e < 9; ++e) mx = fmaxf(mx, s_att[ah * 9 + e]);
            ex = __expf(a - mx);
            s_exp[o] = ex;
        }
        __syncthreads();

        // ---- rbar_h[k] = sum_e exp[e,h]*raw10_e[k] (lanes<40, unnormalized) --
        if (o < 40) {
            float rb = 0.f;
            #pragma unroll
            for (int e = 0; e < 9; ++e) {
                float x = (gk < 6) ? s_seq[e * 6 + gk] : s_et[e * 4 + (gk - 6)];
                rb = fmaf(s_exp[gh * 9 + e], x, rb);
            }
            s_rbar[o] = rb;
        }
        __syncthreads();

        // ---- ctx[o]: normalize at the end (both terms linear in p) ----
        {
            float ssum = 0.f;
            #pragma unroll
            for (int e = 0; e < 9; ++e) ssum += s_exp[h_o * 9 + e];
            float acc = 0.f;
            #pragma unroll
            for (int k = 0; k < 10; ++k) acc = fmaf(s_rbar[h_o * 10 + k], Wvfr[k], acc);
            #pragma unroll
            for (int e = 0; e < 9; ++e) acc = fmaf(s_exp[h_o * 9 + e], Cer[e], acc);
            ctx[p * 64 + o] = acc * (1.0f / ssum);
        }
        // no trailing barrier: next stage writes s_seq/s_et/s_mask which this
        // phase does not read; all s_exp/s_rbar re-writes are >=3 barriers away
    }
}

// ---------------------------------------------------------------------------
// Kernel C v9: MFMA LSTM (unchanged from R1; ~200 us, next round's target).
// ---------------------------------------------------------------------------
#define MFMA16(A, B, C) __builtin_amdgcn_mfma_f32_16x16x32_bf16(A, B, C, 0, 0, 0)

__global__ __launch_bounds__(512, 2) void lstm_mfma(
    const float*  __restrict__ ctx,    // [BS,SEQ,64]
    const bf16x8* __restrict__ whF,    // 16384 frags
    const bf16x8* __restrict__ wiFg,   // 8192 frags
    const float*  __restrict__ b_ih, const float* __restrict__ b_hh,
    const float*  __restrict__ W_out, const float* __restrict__ b_out,
    float* __restrict__ out)           // [BS,64]
{
    const int t  = threadIdx.x;
    const int w  = t >> 6, l = t & 63;
    const int lm = l & 15, lq = l >> 4;
    const int row0 = blockIdx.x * 16;

    __shared__ bf16x8 s_wi[8192];                       // 128 KB  W_ih frags
    __shared__ unsigned short s_xh[1024], s_xl[1024];   // [16][64]  swizzled
    __shared__ unsigned short s_hh[2048], s_hl[2048];   // [16][128] swizzled

    for (int i = t; i < 8192; i += 512) s_wi[i] = wiFg[i];

    bf16x8 whr[4][4][2];
    #pragma unroll
    for (int ti = 0; ti < 4; ++ti)
        #pragma unroll
        for (int kc = 0; kc < 4; ++kc)
            #pragma unroll
            for (int p = 0; p < 2; ++p)
                whr[ti][kc][p] = whF[(((w * 4 + ti) * 4 + kc) * 2 + p) * 64 + l];

    const int m = w * 16 + lm;
    const float bi  = b_ih[m]       + b_hh[m];
    const float bff = b_ih[128 + m] + b_hh[128 + m];
    const float bg  = b_ih[256 + m] + b_hh[256 + m];
    const float bo  = b_ih[384 + m] + b_hh[384 + m];

    float c[4] = {0.f, 0.f, 0.f, 0.f};

    const int xrow = t >> 5;
    const int xl32 = t & 31;
    const float2* ctx2 = (const float2*)ctx;
    const int xbase = (row0 + xrow) * SEQ;
    const int xwb   = xrow * 128 + ((4 * xl32) ^ ((xrow & 7) << 4));
    const int swzr  = (lm & 7) << 4;
    const int hwb_m = 32 * w + 2 * lm;

    for (int s = 0; s < SEQ; ++s) {
        float2 xv = ctx2[(xbase + s) * 32 + xl32];
        unsigned short xh0 = bfrn(xv.x), xh1 = bfrn(xv.y);
        unsigned short xl0 = bfrn(xv.x - bf2f(xh0)), xl1 = bfrn(xv.y - bf2f(xh1));
        *(unsigned int*)((char*)s_xh + xwb) = (unsigned int)xh0 | ((unsigned int)xh1 << 16);
        *(unsigned int*)((char*)s_xl + xwb) = (unsigned int)xl0 | ((unsigned int)xl1 << 16);
        __syncthreads();

        bf16x8 xfh[2], xfl[2];
        #pragma unroll
        for (int kc = 0; kc < 2; ++kc) {
            int b = lm * 128 + ((kc * 64 + lq * 16) ^ swzr);
            xfh[kc] = *(const bf16x8*)((const char*)s_xh + b);
            xfl[kc] = *(const bf16x8*)((const char*)s_xl + b);
        }
        bf16x8 hfh[4], hfl[4];
        if (s > 0) {
            #pragma unroll
            for (int kc = 0; kc < 4; ++kc) {
                int b = lm * 256 + ((kc * 64 + lq * 16) ^ swzr);
                hfh[kc] = *(const bf16x8*)((const char*)s_hh + b);
                hfl[kc] = *(const bf16x8*)((const char*)s_hl + b);
            }
        }

        f32x4 a0 = {0.f,0.f,0.f,0.f}, a1 = a0, a2 = a0, a3 = a0;
        #pragma unroll
        for (int kc = 0; kc < 2; ++kc) {
            bf16x8 wihi[4], wilo[4];
            #pragma unroll
            for (int ti = 0; ti < 4; ++ti) {
                int base = (((w + 8 * ti) * 2 + kc) * 2) * 64 + l;
                wihi[ti] = s_wi[base];
                wilo[ti] = s_wi[base + 64];
            }
            a0 = MFMA16(xfh[kc], wihi[0], a0); a1 = MFMA16(xfh[kc], wihi[1], a1);
            a2 = MFMA16(xfh[kc], wihi[2], a2); a3 = MFMA16(xfh[kc], wihi[3], a3);
            a0 = MFMA16(xfl[kc], wihi[0], a0); a1 = MFMA16(xfl[kc], wihi[1], a1);
            a2 = MFMA16(xfl[kc], wihi[2], a2); a3 = MFMA16(xfl[kc], wihi[3], a3);
            a0 = MFMA16(xfh[kc], wilo[0], a0); a1 = MFMA16(xfh[kc], wilo[1], a1);
            a2 = MFMA16(xfh[kc], wilo[2], a2); a3 = MFMA16(xfh[kc], wilo[3], a3);
        }
        if (s > 0) {
            #pragma unroll
            for (int kc = 0; kc < 4; ++kc) {
                a0 = MFMA16(hfh[kc], whr[0][kc][0], a0); a1 = MFMA16(hfh[kc], whr[1][kc][0], a1);
                a2 = MFMA16(hfh[kc], whr[2][kc][0], a2); a3 = MFMA16(hfh[kc], whr[3][kc][0], a3);
                a0 = MFMA16(hfl[kc], whr[0][kc][0], a0); a1 = MFMA16(hfl[kc], whr[1][kc][0], a1);
                a2 = MFMA16(hfl[kc], whr[2][kc][0], a2); a3 = MFMA16(hfl[kc], whr[3][kc][0], a3);
                a0 = MFMA16(hfh[kc], whr[0][kc][1], a0); a1 = MFMA16(hfh[kc], whr[1][kc][1], a1);
                a2 = MFMA16(hfh[kc], whr[2][kc][1], a2); a3 = MFMA16(hfh[kc], whr[3][kc][1], a3);
            }
        }
        __syncthreads();

        #pragma unroll
        for (int r = 0; r < 4; ++r) {
            float ig = sigf(a0[r] + bi);
            float fg = sigf(a1[r] + bff);
            float gt = tanhfast(a2[r] + bg);
            float og = sigf(a3[r] + bo);
            c[r] = fmaf(fg, c[r], ig * gt);
            float h = og * tanhfast(c[r]);
            unsigned short hh_ = bfrn(h);
            unsigned short hl_ = bfrn(h - bf2f(hh_));
            int row = lq * 4 + r;
            int b = row * 256 + (hwb_m ^ ((row & 7) << 4));
            *(unsigned short*)((char*)s_hh + b) = hh_;
            *(unsigned short*)((char*)s_hl + b) = hl_;
        }
    }
    __syncthreads();

    {
        const int row = t >> 5;
        const int j0 = t & 31, j1 = (t & 31) + 32;
        const int rswz = (row & 7) << 4;
        float accA = b_out[j0], accB = b_out[j1];
        #pragma unroll
        for (int kq = 0; kq < 16; ++kq) {
            int b = row * 256 + ((kq * 16) ^ rswz);
            bf16x8 hh8 = *(const bf16x8*)((const char*)s_hh + b);
            bf16x8 hl8 = *(const bf16x8*)((const char*)s_hl + b);
            #pragma unroll
            for (int e = 0; e < 8; ++e) {
                float h = bf2f((unsigned short)hh8[e]) + bf2f((unsigned short)hl8[e]);
                int k = kq * 8 + e;
                accA = fmaf(h, W_out[j0 * 128 + k], accA);
                accB = fmaf(h, W_out[j1 * 128 + k], accB);
            }
        }
        out[(row0 + row) * 64 + j0] = accA;
        out[(row0 + row) * 64 + j1] = accB;
    }
}

// ---------------------------------------------------------------------------
extern "C" void kernel_launch(void* const* d_in, const int* in_sizes, int n_in,
                              void* d_out, int out_size, void* d_ws, size_t ws_size,
                              hipStream_t stream) {
    (void)in_sizes; (void)n_in; (void)out_size; (void)ws_size;
    const float* seqs  = (const float*)d_in[0];
    const float* ets   = (const float*)d_in[1];
    const int*   masks = (const int*)d_in[2];
    const float* Wf  = (const float*)d_in[3];
    const float* bf  = (const float*)d_in[4];
    const float* Wk  = (const float*)d_in[5];
    const float* bk  = (const float*)d_in[6];
    const float* Wq  = (const float*)d_in[7];
    const float* bq  = (const float*)d_in[8];
    const float* Wv  = (const float*)d_in[9];
    const float* bv  = (const float*)d_in[10];
    const float* Wih = (const float*)d_in[11];
    const float* Whh = (const float*)d_in[12];
    const float* bih = (const float*)d_in[13];
    const float* bhh = (const float*)d_in[14];
    const float* Wo  = (const float*)d_in[15];
    const float* bo  = (const float*)d_in[16];

    // ws layout: whF 256K | wiF 128K | ctx 26.2M  (attn tables in device globals)
    char* ws = (char*)d_ws;
    bf16x8* whF = (bf16x8*)(ws);
    bf16x8* wiF = (bf16x8*)(ws + 262144);
    float*  ctx = (float*) (ws + 262144 + 131072);

    hipLaunchKernelGGL(prep_all, dim3(53), dim3(512), 0, stream,
                       Wih, Whh, whF, wiF, Wf, bf, Wq, bq, Wv);
    hipLaunchKernelGGL(edge_attn_ctx, dim3(4096), dim3(64), 0, stream,
                       seqs, ets, masks, Wk, bk, bv, ctx);
    hipLaunchKernelGGL(lstm_mfma, dim3(128), dim3(512), 0, stream,
                       ctx, whF, wiF, bih, bhh, Wo, bo, (float*)d_out);
}

// Round 3
// 297.800 us; speedup vs baseline: 2.6935x; 1.0469x over previous
//
#include <hip/hip_runtime.h>
#include <math.h>

#define BS   2048
#define SEQ  50
#define NPOS (BS * SEQ)

typedef __attribute__((ext_vector_type(8))) short bf16x8;   // 8 bf16 = 4 VGPR
typedef __attribute__((ext_vector_type(4))) float f32x4;

__device__ __forceinline__ float sigf(float x) { return 1.0f / (1.0f + __expf(-x)); }
__device__ __forceinline__ float tanhfast(float x) {
    float e = __expf(2.0f * x);
    return 1.0f - 2.0f / (e + 1.0f);
}
__device__ __forceinline__ unsigned short bfrn(float x) {   // fp32 -> bf16 rne
    unsigned int u = __float_as_uint(x);
    u += 0x7FFFu + ((u >> 16) & 1u);
    return (unsigned short)(u >> 16);
}
__device__ __forceinline__ float bf2f(unsigned short h) {
    return __uint_as_float(((unsigned int)h) << 16);
}

#define FMA4(A, X, W) \
    A = fmaf((X).x, (W).x, A); A = fmaf((X).y, (W).y, A); \
    A = fmaf((X).z, (W).z, A); A = fmaf((X).w, (W).w, A);

// ---------------------------------------------------------------------------
// Precomputed attention tables (position-independent, built by prep kernel).
// ---------------------------------------------------------------------------
__device__ float G_d[640];
__device__ float D_d[576];
__device__ float Wvf_d[640];
__device__ float Ce_d[576];

// ---------------------------------------------------------------------------
// prep: blocks 0..47 build MFMA weight fragments; blocks 48..52 attn tables.
// ---------------------------------------------------------------------------
__global__ __launch_bounds__(512) void prep_all(
    const float* __restrict__ Wih, const float* __restrict__ Whh,
    bf16x8* __restrict__ whF, bf16x8* __restrict__ wiF,
    const float* __restrict__ Wf, const float* __restrict__ bf,
    const float* __restrict__ Wq, const float* __restrict__ bq,
    const float* __restrict__ Wv)
{
    int id = blockIdx.x * 512 + threadIdx.x;
    if (id < 24576) {
        const float* src;
        bf16x8* dst;
        int p;
        if (id < 16384) {
            int l = id & 63, frag = id >> 6;        // 0..255
            p = frag & 1;
            int kc = (frag >> 1) & 3, ti = (frag >> 3) & 3, w = frag >> 5;
            int n  = (w + 8 * ti) * 16 + (l & 15);
            int k0 = kc * 32 + (l >> 4) * 8;
            src = &Whh[n * 128 + k0];
            dst = &whF[frag * 64 + l];
        } else {
            int id2 = id - 16384;
            int l = id2 & 63, frag = id2 >> 6;      // 0..127
            p = frag & 1;
            int kc = (frag >> 1) & 1, tile = frag >> 2;
            int n  = tile * 16 + (l & 15);
            int k0 = kc * 32 + (l >> 4) * 8;
            src = &Wih[n * 64 + k0];
            dst = &wiF[frag * 64 + l];
        }
        bf16x8 v;
        #pragma unroll
        for (int j = 0; j < 8; ++j) {
            float x = src[j];
            unsigned short hi = bfrn(x);
            unsigned short r  = p ? bfrn(x - bf2f(hi)) : hi;
            v[j] = (short)r;
        }
        *dst = v;
        return;
    }
    int i = id - 24576;
    if (i >= 2432) return;
    if (i < 640) {                       // G[n][k]
        int n = i / 10, k = i % 10;
        float s = 0.f;
        #pragma unroll 8
        for (int j = 0; j < 64; ++j) s = fmaf(Wq[n * 64 + j], Wf[j * 19 + k], s);
        G_d[i] = s;
    } else if (i < 1216) {               // D[e][n]
        int i2 = i - 640;
        int e = i2 >> 6, n = i2 & 63;
        float s = bq[n];
        #pragma unroll 8
        for (int j = 0; j < 64; ++j)
            s = fmaf(Wf[j * 19 + 10 + e] + bf[j], Wq[n * 64 + j], s);
        D_d[i2] = s;
    } else if (i < 1856) {               // Wvf[o][k]
        int i3 = i - 1216;
        int o = i3 / 10, k = i3 % 10;
        float s = 0.f;
        #pragma unroll 8
        for (int j = 0; j < 64; ++j) s = fmaf(Wv[o * 64 + j], Wf[j * 19 + k], s);
        Wvf_d[i3] = s;
    } else {                             // Ce[o][e]
        int i4 = i - 1856;
        int o = i4 / 9, e = i4 % 9;
        float s = 0.f;
        #pragma unroll 8
        for (int j = 0; j < 64; ++j)
            s = fmaf(Wf[j * 19 + 10 + e] + bf[j], Wv[o * 64 + j], s);
        Ce_d[i4] = s;
    }
}

// ---------------------------------------------------------------------------
// Kernel A v2: algebraically-collapsed attention (unchanged from R1, ~120 us).
// ---------------------------------------------------------------------------
__global__ __launch_bounds__(64, 4) void edge_attn_ctx(
    const float* __restrict__ seqs,   // [BS,SEQ,3,3,6]
    const float* __restrict__ ets,    // [BS,SEQ,3,3,4]
    const int*   __restrict__ masks,  // [BS,SEQ,3,3]
    const float* __restrict__ Wk, const float* __restrict__ bk,
    const float* __restrict__ bv,
    float* __restrict__ ctx)          // [BS,SEQ,64]
{
    const int o   = threadIdx.x;
    const int h_o = o >> 4;
    const int lg  = (o < 40) ? o : 0;     // g/rbar lanes: (gh, gk)
    const int gh  = lg / 10, gk = lg % 10;
    const int la  = (o < 36) ? o : 0;     // att lanes: (ah, ae), l = ah*9+ae
    const int ah  = la / 9,  ae = la % 9;

    const float* wkp = &Wk[o * 6];
    const float wk0 = wkp[0], wk1 = wkp[1], wk2 = wkp[2],
                wk3 = wkp[3], wk4 = wkp[4], wk5 = wkp[5];
    const float bkr = bk[o];

    float Greg[16], Dreg[16];
    #pragma unroll
    for (int d = 0; d < 16; ++d) Greg[d] = G_d[(gh * 16 + d) * 10 + gk];
    #pragma unroll
    for (int d = 0; d < 16; ++d) Dreg[d] = D_d[ae * 64 + ah * 16 + d];
    float Wvfr[10];
    #pragma unroll
    for (int k = 0; k < 10; ++k) Wvfr[k] = Wvf_d[o * 10 + k];
    const float bvr = bv[o];
    float Cer[9];
    #pragma unroll
    for (int e = 0; e < 9; ++e) Cer[e] = Ce_d[o * 9 + e] + bvr;

    __shared__ float s_seq[54], s_et[36], s_key[64], s_g[40];
    __shared__ float s_att[36], s_exp[36], s_rbar[40];
    __shared__ int   s_mask[9];

    float r_seq = 0.f, r_et = 0.f; int r_mask = 0;
    {
        int p0 = blockIdx.x;
        if (o < 54) r_seq  = seqs[p0 * 54 + o];
        if (o < 36) r_et   = ets[p0 * 36 + o];
        if (o < 9)  r_mask = masks[p0 * 9 + o];
    }

    for (int p = blockIdx.x; p < NPOS; p += gridDim.x) {
        if (o < 54) s_seq[o]  = r_seq;
        if (o < 36) s_et[o]   = r_et;
        if (o < 9)  s_mask[o] = r_mask;
        __syncthreads();

        {
            int pn = p + gridDim.x;
            if (pn < NPOS) {
                if (o < 54) r_seq  = seqs[pn * 54 + o];
                if (o < 36) r_et   = ets[pn * 36 + o];
                if (o < 9)  r_mask = masks[pn * 9 + o];
            }
        }
        float key = bkr;
        key = fmaf(s_seq[24], wk0, key);
        key = fmaf(s_seq[25], wk1, key);
        key = fmaf(s_seq[26], wk2, key);
        key = fmaf(s_seq[27], wk3, key);
        key = fmaf(s_seq[28], wk4, key);
        key = fmaf(s_seq[29], wk5, key);
        s_key[o] = key;
        __syncthreads();

        float tt = 0.f;
        if (o < 40) {
            float g = 0.f;
            #pragma unroll
            for (int d = 0; d < 16; ++d) g = fmaf(Greg[d], s_key[gh * 16 + d], g);
            s_g[o] = g;
        }
        if (o < 36) {
            #pragma unroll
            for (int d = 0; d < 16; ++d) tt = fmaf(Dreg[d], s_key[ah * 16 + d], tt);
        }
        __syncthreads();

        float a = 0.f;
        if (o < 36) {
            a = tt;
            #pragma unroll
            for (int k = 0; k < 6; ++k) a = fmaf(s_seq[ae * 6 + k], s_g[ah * 10 + k], a);
            #pragma unroll
            for (int k = 0; k < 4; ++k) a = fmaf(s_et[ae * 4 + k], s_g[ah * 10 + 6 + k], a);
            a *= 0.25f;
            if (s_mask[ae] == 0) a = -1.0e10f;
            s_att[o] = a;
        }
        __syncthreads();

        float ex = 0.f;
        if (o < 36) {
            float mx = s_att[ah * 9 + 0];
            #pragma unroll
            for (int e = 1; e < 9; ++e) mx = fmaxf(mx, s_att[ah * 9 + e]);
            ex = __expf(a - mx);
            s_exp[o] = ex;
        }
        __syncthreads();

        if (o < 40) {
            float rb = 0.f;
            #pragma unroll
            for (int e = 0; e < 9; ++e) {
                float x = (gk < 6) ? s_seq[e * 6 + gk] : s_et[e * 4 + (gk - 6)];
                rb = fmaf(s_exp[gh * 9 + e], x, rb);
            }
            s_rbar[o] = rb;
        }
        __syncthreads();

        {
            float ssum = 0.f;
            #pragma unroll
            for (int e = 0; e < 9; ++e) ssum += s_exp[h_o * 9 + e];
            float acc = 0.f;
            #pragma unroll
            for (int k = 0; k < 10; ++k) acc = fmaf(s_rbar[h_o * 10 + k], Wvfr[k], acc);
            #pragma unroll
            for (int e = 0; e < 9; ++e) acc = fmaf(s_exp[h_o * 9 + e], Cer[e], acc);
            ctx[p * 64 + o] = acc * (1.0f / ssum);
        }
    }
}

// ---------------------------------------------------------------------------
// Kernel C v10: MFMA LSTM. 256 blocks x 512 thr (8 waves), 8 batch rows/block
// (M-tile rows 8..15 are zero -> junk C rows, discarded; fills all 256 CUs).
//  - ctx for step s+1 prefetched into regs right after B1 (latency spans the
//    whole MFMA+pointwise phase).
//  - B2 moved to right after the x/h fragment ds_reads: MFMA + pointwise +
//    stores run in the barrier-free span (s_wi is never rewritten -> its
//    reads need no barrier protection).
// ---------------------------------------------------------------------------
#define MFMA16(A, B, C) __builtin_amdgcn_mfma_f32_16x16x32_bf16(A, B, C, 0, 0, 0)

__global__ __launch_bounds__(512, 2) void lstm_mfma(
    const float*  __restrict__ ctx,    // [BS,SEQ,64]
    const bf16x8* __restrict__ whF,    // 16384 frags
    const bf16x8* __restrict__ wiFg,   // 8192 frags
    const float*  __restrict__ b_ih, const float* __restrict__ b_hh,
    const float*  __restrict__ W_out, const float* __restrict__ b_out,
    float* __restrict__ out)           // [BS,64]
{
    const int t  = threadIdx.x;
    const int w  = t >> 6, l = t & 63;
    const int lm = l & 15, lq = l >> 4;
    const int row0 = blockIdx.x * 8;            // 8 rows per block

    __shared__ bf16x8 s_wi[8192];                       // 128 KB  W_ih frags
    __shared__ unsigned short s_xh[1024], s_xl[1024];   // [16][64]  swizzled
    __shared__ unsigned short s_hh[2048], s_hl[2048];   // [16][128] swizzled

    for (int i = t; i < 8192; i += 512) s_wi[i] = wiFg[i];
    // zero all x/h staging once (rows 8..15 stay zero forever)
    for (int i = t; i < 1024; i += 512) { s_xh[i] = 0; s_xl[i] = 0; }
    for (int i = t; i < 2048; i += 512) { s_hh[i] = 0; s_hl[i] = 0; }

    bf16x8 whr[4][4][2];
    #pragma unroll
    for (int ti = 0; ti < 4; ++ti)
        #pragma unroll
        for (int kc = 0; kc < 4; ++kc)
            #pragma unroll
            for (int p = 0; p < 2; ++p)
                whr[ti][kc][p] = whF[(((w * 4 + ti) * 4 + kc) * 2 + p) * 64 + l];

    const int m = w * 16 + lm;
    const float bi  = b_ih[m]       + b_hh[m];
    const float bff = b_ih[128 + m] + b_hh[128 + m];
    const float bg  = b_ih[256 + m] + b_hh[256 + m];
    const float bo  = b_ih[384 + m] + b_hh[384 + m];

    float c[4] = {0.f, 0.f, 0.f, 0.f};

    const int xrow = t >> 5;                   // 0..15; only <8 are real rows
    const int xl32 = t & 31;
    const bool xact = (xrow < 8);
    const float2* ctx2 = (const float2*)ctx;
    const int xbase = (row0 + (xact ? xrow : 0)) * SEQ;
    const int xwb   = xrow * 128 + ((4 * xl32) ^ ((xrow & 7) << 4));
    const int swzr  = (lm & 7) << 4;
    const int hwb_m = 32 * w + 2 * lm;

    // prefetch step 0
    float2 xv = make_float2(0.f, 0.f);
    if (xact) xv = ctx2[xbase * 32 + xl32];

    for (int s = 0; s < SEQ; ++s) {
        // ---- stage x(s) from prefetched regs (rows < 8 only) ----
        if (xact) {
            unsigned short xh0 = bfrn(xv.x), xh1 = bfrn(xv.y);
            unsigned short xl0 = bfrn(xv.x - bf2f(xh0)), xl1 = bfrn(xv.y - bf2f(xh1));
            *(unsigned int*)((char*)s_xh + xwb) = (unsigned int)xh0 | ((unsigned int)xh1 << 16);
            *(unsigned int*)((char*)s_xl + xwb) = (unsigned int)xl0 | ((unsigned int)xl1 << 16);
        }
        __syncthreads();   // B1: x(s) + h(s-1) visible

        // ---- issue prefetch for step s+1 (consumed after the compute phase)
        float2 xvn = make_float2(0.f, 0.f);
        if (xact && s + 1 < SEQ) xvn = ctx2[(xbase + s + 1) * 32 + xl32];

        // ---- x/h fragment ds_reads ----
        bf16x8 xfh[2], xfl[2];
        #pragma unroll
        for (int kc = 0; kc < 2; ++kc) {
            int b = lm * 128 + ((kc * 64 + lq * 16) ^ swzr);
            xfh[kc] = *(const bf16x8*)((const char*)s_xh + b);
            xfl[kc] = *(const bf16x8*)((const char*)s_xl + b);
        }
        bf16x8 hfh[4], hfl[4];
        if (s > 0) {
            #pragma unroll
            for (int kc = 0; kc < 4; ++kc) {
                int b = lm * 256 + ((kc * 64 + lq * 16) ^ swzr);
                hfh[kc] = *(const bf16x8*)((const char*)s_hh + b);
                hfl[kc] = *(const bf16x8*)((const char*)s_hl + b);
            }
        }
        __syncthreads();   // B2: staging reads done; writes below are safe

        // ---- MFMA phase (register + s_wi only; barrier-free span) ----
        f32x4 a0 = {0.f,0.f,0.f,0.f}, a1 = a0, a2 = a0, a3 = a0;
        #pragma unroll
        for (int kc = 0; kc < 2; ++kc) {
            bf16x8 wihi[4], wilo[4];
            #pragma unroll
            for (int ti = 0; ti < 4; ++ti) {
                int base = (((w + 8 * ti) * 2 + kc) * 2) * 64 + l;
                wihi[ti] = s_wi[base];
                wilo[ti] = s_wi[base + 64];
            }
            a0 = MFMA16(xfh[kc], wihi[0], a0); a1 = MFMA16(xfh[kc], wihi[1], a1);
            a2 = MFMA16(xfh[kc], wihi[2], a2); a3 = MFMA16(xfh[kc], wihi[3], a3);
            a0 = MFMA16(xfl[kc], wihi[0], a0); a1 = MFMA16(xfl[kc], wihi[1], a1);
            a2 = MFMA16(xfl[kc], wihi[2], a2); a3 = MFMA16(xfl[kc], wihi[3], a3);
            a0 = MFMA16(xfh[kc], wilo[0], a0); a1 = MFMA16(xfh[kc], wilo[1], a1);
            a2 = MFMA16(xfh[kc], wilo[2], a2); a3 = MFMA16(xfh[kc], wilo[3], a3);
        }
        if (s > 0) {
            #pragma unroll
            for (int kc = 0; kc < 4; ++kc) {
                a0 = MFMA16(hfh[kc], whr[0][kc][0], a0); a1 = MFMA16(hfh[kc], whr[1][kc][0], a1);
                a2 = MFMA16(hfh[kc], whr[2][kc][0], a2); a3 = MFMA16(hfh[kc], whr[3][kc][0], a3);
                a0 = MFMA16(hfl[kc], whr[0][kc][0], a0); a1 = MFMA16(hfl[kc], whr[1][kc][0], a1);
                a2 = MFMA16(hfl[kc], whr[2][kc][0], a2); a3 = MFMA16(hfl[kc], whr[3][kc][0], a3);
                a0 = MFMA16(hfh[kc], whr[0][kc][1], a0); a1 = MFMA16(hfh[kc], whr[1][kc][1], a1);
                a2 = MFMA16(hfh[kc], whr[2][kc][1], a2); a3 = MFMA16(hfh[kc], whr[3][kc][1], a3);
            }
        }

        // ---- pointwise + h write (rows < 8 only persist) ----
        #pragma unroll
        for (int r = 0; r < 4; ++r) {
            float ig = sigf(a0[r] + bi);
            float fg = sigf(a1[r] + bff);
            float gt = tanhfast(a2[r] + bg);
            float og = sigf(a3[r] + bo);
            c[r] = fmaf(fg, c[r], ig * gt);
            float h = og * tanhfast(c[r]);
            int row = lq * 4 + r;
            if (row < 8) {
                unsigned short hh_ = bfrn(h);
                unsigned short hl_ = bfrn(h - bf2f(hh_));
                int b = row * 256 + (hwb_m ^ ((row & 7) << 4));
                *(unsigned short*)((char*)s_hh + b) = hh_;
                *(unsigned short*)((char*)s_hl + b) = hl_;
            }
        }
        xv = xvn;
    }
    __syncthreads();

    // ---- epilogue: out[row][j] = b_out[j] + h[row] . W_out[j], rows < 8 ----
    {
        const int row = t >> 5;
        if (row < 8) {
            const int j0 = t & 31, j1 = (t & 31) + 32;
            const int rswz = (row & 7) << 4;
            float accA = b_out[j0], accB = b_out[j1];
            #pragma unroll
            for (int kq = 0; kq < 16; ++kq) {
                int b = row * 256 + ((kq * 16) ^ rswz);
                bf16x8 hh8 = *(const bf16x8*)((const char*)s_hh + b);
                bf16x8 hl8 = *(const bf16x8*)((const char*)s_hl + b);
                #pragma unroll
                for (int e = 0; e < 8; ++e) {
                    float h = bf2f((unsigned short)hh8[e]) + bf2f((unsigned short)hl8[e]);
                    int k = kq * 8 + e;
                    accA = fmaf(h, W_out[j0 * 128 + k], accA);
                    accB = fmaf(h, W_out[j1 * 128 + k], accB);
                }
            }
            out[(row0 + row) * 64 + j0] = accA;
            out[(row0 + row) * 64 + j1] = accB;
        }
    }
}

// ---------------------------------------------------------------------------
extern "C" void kernel_launch(void* const* d_in, const int* in_sizes, int n_in,
                              void* d_out, int out_size, void* d_ws, size_t ws_size,
                              hipStream_t stream) {
    (void)in_sizes; (void)n_in; (void)out_size; (void)ws_size;
    const float* seqs  = (const float*)d_in[0];
    const float* ets   = (const float*)d_in[1];
    const int*   masks = (const int*)d_in[2];
    const float* Wf  = (const float*)d_in[3];
    const float* bf  = (const float*)d_in[4];
    const float* Wk  = (const float*)d_in[5];
    const float* bk  = (const float*)d_in[6];
    const float* Wq  = (const float*)d_in[7];
    const float* bq  = (const float*)d_in[8];
    const float* Wv  = (const float*)d_in[9];
    const float* bv  = (const float*)d_in[10];
    const float* Wih = (const float*)d_in[11];
    const float* Whh = (const float*)d_in[12];
    const float* bih = (const float*)d_in[13];
    const float* bhh = (const float*)d_in[14];
    const float* Wo  = (const float*)d_in[15];
    const float* bo  = (const float*)d_in[16];

    // ws layout: whF 256K | wiF 128K | ctx 26.2M  (attn tables in device globals)
    char* ws = (char*)d_ws;
    bf16x8* whF = (bf16x8*)(ws);
    bf16x8* wiF = (bf16x8*)(ws + 262144);
    float*  ctx = (float*) (ws + 262144 + 131072);

    hipLaunchKernelGGL(prep_all, dim3(53), dim3(512), 0, stream,
                       Wih, Whh, whF, wiF, Wf, bf, Wq, bq, Wv);
    hipLaunchKernelGGL(edge_attn_ctx, dim3(4096), dim3(64), 0, stream,
                       seqs, ets, masks, Wk, bk, bv, ctx);
    hipLaunchKernelGGL(lstm_mfma, dim3(256), dim3(512), 0, stream,
                       ctx, whF, wiF, bih, bhh, Wo, bo, (float*)d_out);
}

// Round 4
// 285.782 us; speedup vs baseline: 2.8067x; 1.0421x over previous
//
#include <hip/hip_runtime.h>
#include <math.h>

#define BS   2048
#define SEQ  50
#define NPOS (BS * SEQ)

typedef __attribute__((ext_vector_type(8))) short bf16x8;   // 8 bf16 = 4 VGPR
typedef __attribute__((ext_vector_type(4))) float f32x4;

__device__ __forceinline__ float sigf(float x) { return 1.0f / (1.0f + __expf(-x)); }
__device__ __forceinline__ float tanhfast(float x) {
    float e = __expf(2.0f * x);
    return 1.0f - 2.0f / (e + 1.0f);
}
__device__ __forceinline__ unsigned short bfrn(float x) {   // fp32 -> bf16 rne
    unsigned int u = __float_as_uint(x);
    u += 0x7FFFu + ((u >> 16) & 1u);
    return (unsigned short)(u >> 16);
}
__device__ __forceinline__ float bf2f(unsigned short h) {
    return __uint_as_float(((unsigned int)h) << 16);
}

#define FMA4(A, X, W) \
    A = fmaf((X).x, (W).x, A); A = fmaf((X).y, (W).y, A); \
    A = fmaf((X).z, (W).z, A); A = fmaf((X).w, (W).w, A);

// ---------------------------------------------------------------------------
// Precomputed attention tables (position-independent, built by prep kernel).
// ---------------------------------------------------------------------------
__device__ float G_d[640];
__device__ float D_d[576];
__device__ float Wvf_d[640];
__device__ float Ce_d[576];

// ---------------------------------------------------------------------------
// prep: blocks 0..47 build MFMA weight fragments; blocks 48..52 attn tables.
// ---------------------------------------------------------------------------
__global__ __launch_bounds__(512) void prep_all(
    const float* __restrict__ Wih, const float* __restrict__ Whh,
    bf16x8* __restrict__ whF, bf16x8* __restrict__ wiF,
    const float* __restrict__ Wf, const float* __restrict__ bf,
    const float* __restrict__ Wq, const float* __restrict__ bq,
    const float* __restrict__ Wv)
{
    int id = blockIdx.x * 512 + threadIdx.x;
    if (id < 24576) {
        const float* src;
        bf16x8* dst;
        int p;
        if (id < 16384) {
            int l = id & 63, frag = id >> 6;        // 0..255
            p = frag & 1;
            int kc = (frag >> 1) & 3, ti = (frag >> 3) & 3, w = frag >> 5;
            int n  = (w + 8 * ti) * 16 + (l & 15);
            int k0 = kc * 32 + (l >> 4) * 8;
            src = &Whh[n * 128 + k0];
            dst = &whF[frag * 64 + l];
        } else {
            int id2 = id - 16384;
            int l = id2 & 63, frag = id2 >> 6;      // 0..127
            p = frag & 1;
            int kc = (frag >> 1) & 1, tile = frag >> 2;
            int n  = tile * 16 + (l & 15);
            int k0 = kc * 32 + (l >> 4) * 8;
            src = &Wih[n * 64 + k0];
            dst = &wiF[frag * 64 + l];
        }
        bf16x8 v;
        #pragma unroll
        for (int j = 0; j < 8; ++j) {
            float x = src[j];
            unsigned short hi = bfrn(x);
            unsigned short r  = p ? bfrn(x - bf2f(hi)) : hi;
            v[j] = (short)r;
        }
        *dst = v;
        return;
    }
    int i = id - 24576;
    if (i >= 2432) return;
    if (i < 640) {                       // G[n][k]
        int n = i / 10, k = i % 10;
        float s = 0.f;
        #pragma unroll 8
        for (int j = 0; j < 64; ++j) s = fmaf(Wq[n * 64 + j], Wf[j * 19 + k], s);
        G_d[i] = s;
    } else if (i < 1216) {               // D[e][n]
        int i2 = i - 640;
        int e = i2 >> 6, n = i2 & 63;
        float s = bq[n];
        #pragma unroll 8
        for (int j = 0; j < 64; ++j)
            s = fmaf(Wf[j * 19 + 10 + e] + bf[j], Wq[n * 64 + j], s);
        D_d[i2] = s;
    } else if (i < 1856) {               // Wvf[o][k]
        int i3 = i - 1216;
        int o = i3 / 10, k = i3 % 10;
        float s = 0.f;
        #pragma unroll 8
        for (int j = 0; j < 64; ++j) s = fmaf(Wv[o * 64 + j], Wf[j * 19 + k], s);
        Wvf_d[i3] = s;
    } else {                             // Ce[o][e]
        int i4 = i - 1856;
        int o = i4 / 9, e = i4 % 9;
        float s = 0.f;
        #pragma unroll 8
        for (int j = 0; j < 64; ++j)
            s = fmaf(Wf[j * 19 + 10 + e] + bf[j], Wv[o * 64 + j], s);
        Ce_d[i4] = s;
    }
}

// ---------------------------------------------------------------------------
// Kernel A v2: algebraically-collapsed attention (unchanged; ~120 us).
// ---------------------------------------------------------------------------
__global__ __launch_bounds__(64, 4) void edge_attn_ctx(
    const float* __restrict__ seqs,   // [BS,SEQ,3,3,6]
    const float* __restrict__ ets,    // [BS,SEQ,3,3,4]
    const int*   __restrict__ masks,  // [BS,SEQ,3,3]
    const float* __restrict__ Wk, const float* __restrict__ bk,
    const float* __restrict__ bv,
    float* __restrict__ ctx)          // [BS,SEQ,64]
{
    const int o   = threadIdx.x;
    const int h_o = o >> 4;
    const int lg  = (o < 40) ? o : 0;     // g/rbar lanes: (gh, gk)
    const int gh  = lg / 10, gk = lg % 10;
    const int la  = (o < 36) ? o : 0;     // att lanes: (ah, ae), l = ah*9+ae
    const int ah  = la / 9,  ae = la % 9;

    const float* wkp = &Wk[o * 6];
    const float wk0 = wkp[0], wk1 = wkp[1], wk2 = wkp[2],
                wk3 = wkp[3], wk4 = wkp[4], wk5 = wkp[5];
    const float bkr = bk[o];

    float Greg[16], Dreg[16];
    #pragma unroll
    for (int d = 0; d < 16; ++d) Greg[d] = G_d[(gh * 16 + d) * 10 + gk];
    #pragma unroll
    for (int d = 0; d < 16; ++d) Dreg[d] = D_d[ae * 64 + ah * 16 + d];
    float Wvfr[10];
    #pragma unroll
    for (int k = 0; k < 10; ++k) Wvfr[k] = Wvf_d[o * 10 + k];
    const float bvr = bv[o];
    float Cer[9];
    #pragma unroll
    for (int e = 0; e < 9; ++e) Cer[e] = Ce_d[o * 9 + e] + bvr;

    __shared__ float s_seq[54], s_et[36], s_key[64], s_g[40];
    __shared__ float s_att[36], s_exp[36], s_rbar[40];
    __shared__ int   s_mask[9];

    float r_seq = 0.f, r_et = 0.f; int r_mask = 0;
    {
        int p0 = blockIdx.x;
        if (o < 54) r_seq  = seqs[p0 * 54 + o];
        if (o < 36) r_et   = ets[p0 * 36 + o];
        if (o < 9)  r_mask = masks[p0 * 9 + o];
    }

    for (int p = blockIdx.x; p < NPOS; p += gridDim.x) {
        if (o < 54) s_seq[o]  = r_seq;
        if (o < 36) s_et[o]   = r_et;
        if (o < 9)  s_mask[o] = r_mask;
        __syncthreads();

        {
            int pn = p + gridDim.x;
            if (pn < NPOS) {
                if (o < 54) r_seq  = seqs[pn * 54 + o];
                if (o < 36) r_et   = ets[pn * 36 + o];
                if (o < 9)  r_mask = masks[pn * 9 + o];
            }
        }
        float key = bkr;
        key = fmaf(s_seq[24], wk0, key);
        key = fmaf(s_seq[25], wk1, key);
        key = fmaf(s_seq[26], wk2, key);
        key = fmaf(s_seq[27], wk3, key);
        key = fmaf(s_seq[28], wk4, key);
        key = fmaf(s_seq[29], wk5, key);
        s_key[o] = key;
        __syncthreads();

        float tt = 0.f;
        if (o < 40) {
            float g = 0.f;
            #pragma unroll
            for (int d = 0; d < 16; ++d) g = fmaf(Greg[d], s_key[gh * 16 + d], g);
            s_g[o] = g;
        }
        if (o < 36) {
            #pragma unroll
            for (int d = 0; d < 16; ++d) tt = fmaf(Dreg[d], s_key[ah * 16 + d], tt);
        }
        __syncthreads();

        float a = 0.f;
        if (o < 36) {
            a = tt;
            #pragma unroll
            for (int k = 0; k < 6; ++k) a = fmaf(s_seq[ae * 6 + k], s_g[ah * 10 + k], a);
            #pragma unroll
            for (int k = 0; k < 4; ++k) a = fmaf(s_et[ae * 4 + k], s_g[ah * 10 + 6 + k], a);
            a *= 0.25f;
            if (s_mask[ae] == 0) a = -1.0e10f;
            s_att[o] = a;
        }
        __syncthreads();

        float ex = 0.f;
        if (o < 36) {
            float mx = s_att[ah * 9 + 0];
            #pragma unroll
            for (int e = 1; e < 9; ++e) mx = fmaxf(mx, s_att[ah * 9 + e]);
            ex = __expf(a - mx);
            s_exp[o] = ex;
        }
        __syncthreads();

        if (o < 40) {
            float rb = 0.f;
            #pragma unroll
            for (int e = 0; e < 9; ++e) {
                float x = (gk < 6) ? s_seq[e * 6 + gk] : s_et[e * 4 + (gk - 6)];
                rb = fmaf(s_exp[gh * 9 + e], x, rb);
            }
            s_rbar[o] = rb;
        }
        __syncthreads();

        {
            float ssum = 0.f;
            #pragma unroll
            for (int e = 0; e < 9; ++e) ssum += s_exp[h_o * 9 + e];
            float acc = 0.f;
            #pragma unroll
            for (int k = 0; k < 10; ++k) acc = fmaf(s_rbar[h_o * 10 + k], Wvfr[k], acc);
            #pragma unroll
            for (int e = 0; e < 9; ++e) acc = fmaf(s_exp[h_o * 9 + e], Cer[e], acc);
            ctx[p * 64 + o] = acc * (1.0f / ssum);
        }
    }
}

// ---------------------------------------------------------------------------
// Kernel C v11: MFMA LSTM, single-barrier steps.
//  - x/h staging parity-double-buffered (planes alternate by step) -> the
//    read-before-overwrite hazard that required the second barrier is gone:
//    exactly ONE __syncthreads per step.  (Safety: any same-plane write
//    happens strictly after the rendezvous barrier that follows the reads
//    of that plane -- 2-plane reuse distance spans one barrier.)
//  - h-side MFMAs run FIRST (operands fully in registers); the 16 in-loop
//    s_wi reads are consumed by the x-side MFMAs LAST, so their LDS latency
//    hides under the h chains instead of gating the phase head.
//  - ctx prefetched one step ahead (unchanged).
// ---------------------------------------------------------------------------
#define MFMA16(A, B, C) __builtin_amdgcn_mfma_f32_16x16x32_bf16(A, B, C, 0, 0, 0)
#define MM4(F, W0, W1, W2, W3) \
    a0 = MFMA16(F, W0, a0); a1 = MFMA16(F, W1, a1); \
    a2 = MFMA16(F, W2, a2); a3 = MFMA16(F, W3, a3);

__global__ __launch_bounds__(512, 2) void lstm_mfma(
    const float*  __restrict__ ctx,    // [BS,SEQ,64]
    const bf16x8* __restrict__ whF,    // 16384 frags
    const bf16x8* __restrict__ wiFg,   // 8192 frags
    const float*  __restrict__ b_ih, const float* __restrict__ b_hh,
    const float*  __restrict__ W_out, const float* __restrict__ b_out,
    float* __restrict__ out)           // [BS,64]
{
    const int t  = threadIdx.x;
    const int w  = t >> 6, l = t & 63;
    const int lm = l & 15, lq = l >> 4;
    const int row0 = blockIdx.x * 8;            // 8 real rows per block

    __shared__ bf16x8 s_wi[8192];                       // 128 KB  W_ih frags
    __shared__ unsigned short s_xh[2048], s_xl[2048];   // 2 planes [16][64]
    __shared__ unsigned short s_hh[4096], s_hl[4096];   // 2 planes [16][128]

    for (int i = t; i < 8192; i += 512) s_wi[i] = wiFg[i];
    for (int i = t; i < 2048; i += 512) { s_xh[i] = 0; s_xl[i] = 0; }
    for (int i = t; i < 4096; i += 512) { s_hh[i] = 0; s_hl[i] = 0; }

    // W_hh fragments (hi+lo) -> registers for the whole loop
    bf16x8 whr[4][4][2];
    #pragma unroll
    for (int ti = 0; ti < 4; ++ti)
        #pragma unroll
        for (int kc = 0; kc < 4; ++kc)
            #pragma unroll
            for (int p = 0; p < 2; ++p)
                whr[ti][kc][p] = whF[(((w * 4 + ti) * 4 + kc) * 2 + p) * 64 + l];

    const int m = w * 16 + lm;
    const float bi  = b_ih[m]       + b_hh[m];
    const float bff = b_ih[128 + m] + b_hh[128 + m];
    const float bg  = b_ih[256 + m] + b_hh[256 + m];
    const float bo  = b_ih[384 + m] + b_hh[384 + m];

    float c[4] = {0.f, 0.f, 0.f, 0.f};

    const int xrow = t >> 5;                   // 0..15; only <8 are real rows
    const int xl32 = t & 31;
    const bool xact = (xrow < 8);
    const float2* ctx2 = (const float2*)ctx;
    const int xbase = (row0 + (xact ? xrow : 0)) * SEQ;
    const int xwb   = xrow * 128 + ((4 * xl32) ^ ((xrow & 7) << 4));  // bytes in plane
    const int swzr  = (lm & 7) << 4;
    const int hwb_m = 32 * w + 2 * lm;

    // prefetch step 0
    float2 xv = make_float2(0.f, 0.f);
    if (xact) xv = ctx2[xbase * 32 + xl32];

    for (int s = 0; s < SEQ; ++s) {
        const int xpB = (s & 1) * 2048;        // x plane (this step), bytes
        const int hpB = (s & 1) * 4096;        // h plane to WRITE (this step)
        const int hqB = 4096 - hpB;            // h plane to READ  (s-1)

        // ---- stage x(s) from prefetched regs into plane xpB ----
        if (xact) {
            unsigned short xh0 = bfrn(xv.x), xh1 = bfrn(xv.y);
            unsigned short xl0 = bfrn(xv.x - bf2f(xh0)), xl1 = bfrn(xv.y - bf2f(xh1));
            *(unsigned int*)((char*)s_xh + xpB + xwb) = (unsigned int)xh0 | ((unsigned int)xh1 << 16);
            *(unsigned int*)((char*)s_xl + xpB + xwb) = (unsigned int)xl0 | ((unsigned int)xl1 << 16);
        }
        __syncthreads();   // THE step barrier: x(s) and h(s-1) visible

        // ---- issue next-step ctx prefetch ----
        float2 xvn = make_float2(0.f, 0.f);
        if (xact && s + 1 < SEQ) xvn = ctx2[(xbase + s + 1) * 32 + xl32];

        // ---- fragment ds_reads (issued up front, back-to-back) ----
        bf16x8 hfh[4], hfl[4];
        if (s > 0) {
            #pragma unroll
            for (int kc = 0; kc < 4; ++kc) {
                int b = lm * 256 + ((kc * 64 + lq * 16) ^ swzr);
                hfh[kc] = *(const bf16x8*)((const char*)s_hh + hqB + b);
                hfl[kc] = *(const bf16x8*)((const char*)s_hl + hqB + b);
            }
        }
        bf16x8 xfh[2], xfl[2];
        #pragma unroll
        for (int kc = 0; kc < 2; ++kc) {
            int b = lm * 128 + ((kc * 64 + lq * 16) ^ swzr);
            xfh[kc] = *(const bf16x8*)((const char*)s_xh + xpB + b);
            xfl[kc] = *(const bf16x8*)((const char*)s_xl + xpB + b);
        }

        f32x4 a0 = {0.f,0.f,0.f,0.f}, a1 = a0, a2 = a0, a3 = a0;

        // ---- h-side first: 48 MFMAs on pure register operands ----
        if (s > 0) {
            MM4(hfh[0], whr[0][0][0], whr[1][0][0], whr[2][0][0], whr[3][0][0])
            MM4(hfh[1], whr[0][1][0], whr[1][1][0], whr[2][1][0], whr[3][1][0])
            MM4(hfh[2], whr[0][2][0], whr[1][2][0], whr[2][2][0], whr[3][2][0])
            MM4(hfh[3], whr[0][3][0], whr[1][3][0], whr[2][3][0], whr[3][3][0])
            MM4(hfl[0], whr[0][0][0], whr[1][0][0], whr[2][0][0], whr[3][0][0])
            MM4(hfl[1], whr[0][1][0], whr[1][1][0], whr[2][1][0], whr[3][1][0])
            MM4(hfl[2], whr[0][2][0], whr[1][2][0], whr[2][2][0], whr[3][2][0])
            MM4(hfl[3], whr[0][3][0], whr[1][3][0], whr[2][3][0], whr[3][3][0])
            MM4(hfh[0], whr[0][0][1], whr[1][0][1], whr[2][0][1], whr[3][0][1])
            MM4(hfh[1], whr[0][1][1], whr[1][1][1], whr[2][1][1], whr[3][1][1])
            MM4(hfh[2], whr[0][2][1], whr[1][2][1], whr[2][2][1], whr[3][2][1])
            MM4(hfh[3], whr[0][3][1], whr[1][3][1], whr[2][3][1], whr[3][3][1])
        }

        // ---- x-side last: s_wi LDS reads hide under the h chains ----
        #pragma unroll
        for (int kc = 0; kc < 2; ++kc) {
            bf16x8 wihi[4], wilo[4];
            #pragma unroll
            for (int ti = 0; ti < 4; ++ti) {
                int base = (((w + 8 * ti) * 2 + kc) * 2) * 64 + l;
                wihi[ti] = s_wi[base];
                wilo[ti] = s_wi[base + 64];
            }
            MM4(xfh[kc], wihi[0], wihi[1], wihi[2], wihi[3])
            MM4(xfl[kc], wihi[0], wihi[1], wihi[2], wihi[3])
            MM4(xfh[kc], wilo[0], wilo[1], wilo[2], wilo[3])
        }

        // ---- pointwise + h write into plane hpB (rows < 8 persist) ----
        #pragma unroll
        for (int r = 0; r < 4; ++r) {
            float ig = sigf(a0[r] + bi);
            float fg = sigf(a1[r] + bff);
            float gt = tanhfast(a2[r] + bg);
            float og = sigf(a3[r] + bo);
            c[r] = fmaf(fg, c[r], ig * gt);
            float h = og * tanhfast(c[r]);
            int row = lq * 4 + r;
            if (row < 8) {
                unsigned short hh_ = bfrn(h);
                unsigned short hl_ = bfrn(h - bf2f(hh_));
                int b = hpB + row * 256 + (hwb_m ^ ((row & 7) << 4));
                *(unsigned short*)((char*)s_hh + b) = hh_;
                *(unsigned short*)((char*)s_hl + b) = hl_;
            }
        }
        xv = xvn;
    }
    __syncthreads();

    // ---- epilogue: out[row][j] = b_out[j] + h[row] . W_out[j], rows < 8 ----
    {
        const int row = t >> 5;
        if (row < 8) {
            const int lpB = ((SEQ - 1) & 1) * 4096;   // plane of h(SEQ-1)
            const int j0 = t & 31, j1 = (t & 31) + 32;
            const int rswz = (row & 7) << 4;
            float accA = b_out[j0], accB = b_out[j1];
            #pragma unroll
            for (int kq = 0; kq < 16; ++kq) {
                int b = lpB + row * 256 + ((kq * 16) ^ rswz);
                bf16x8 hh8 = *(const bf16x8*)((const char*)s_hh + b);
                bf16x8 hl8 = *(const bf16x8*)((const char*)s_hl + b);
                #pragma unroll
                for (int e = 0; e < 8; ++e) {
                    float h = bf2f((unsigned short)hh8[e]) + bf2f((unsigned short)hl8[e]);
                    int k = kq * 8 + e;
                    accA = fmaf(h, W_out[j0 * 128 + k], accA);
                    accB = fmaf(h, W_out[j1 * 128 + k], accB);
                }
            }
            out[(row0 + row) * 64 + j0] = accA;
            out[(row0 + row) * 64 + j1] = accB;
        }
    }
}

// ---------------------------------------------------------------------------
extern "C" void kernel_launch(void* const* d_in, const int* in_sizes, int n_in,
                              void* d_out, int out_size, void* d_ws, size_t ws_size,
                              hipStream_t stream) {
    (void)in_sizes; (void)n_in; (void)out_size; (void)ws_size;
    const float* seqs  = (const float*)d_in[0];
    const float* ets   = (const float*)d_in[1];
    const int*   masks = (const int*)d_in[2];
    const float* Wf  = (const float*)d_in[3];
    const float* bf  = (const float*)d_in[4];
    const float* Wk  = (const float*)d_in[5];
    const float* bk  = (const float*)d_in[6];
    const float* Wq  = (const float*)d_in[7];
    const float* bq  = (const float*)d_in[8];
    const float* Wv  = (const float*)d_in[9];
    const float* bv  = (const float*)d_in[10];
    const float* Wih = (const float*)d_in[11];
    const float* Whh = (const float*)d_in[12];
    const float* bih = (const float*)d_in[13];
    const float* bhh = (const float*)d_in[14];
    const float* Wo  = (const float*)d_in[15];
    const float* bo  = (const float*)d_in[16];

    // ws layout: whF 256K | wiF 128K | ctx 26.2M  (attn tables in device globals)
    char* ws = (char*)d_ws;
    bf16x8* whF = (bf16x8*)(ws);
    bf16x8* wiF = (bf16x8*)(ws + 262144);
    float*  ctx = (float*) (ws + 262144 + 131072);

    hipLaunchKernelGGL(prep_all, dim3(53), dim3(512), 0, stream,
                       Wih, Whh, whF, wiF, Wf, bf, Wq, bq, Wv);
    hipLaunchKernelGGL(edge_attn_ctx, dim3(4096), dim3(64), 0, stream,
                       seqs, ets, masks, Wk, bk, bv, ctx);
    hipLaunchKernelGGL(lstm_mfma, dim3(256), dim3(512), 0, stream,
                       ctx, whF, wiF, bih, bhh, Wo, bo, (float*)d_out);
}

// Round 5
// 246.179 us; speedup vs baseline: 3.2582x; 1.1609x over previous
//
#include <hip/hip_runtime.h>
#include <math.h>

#define BS   2048
#define SEQ  50
#define NPOS (BS * SEQ)

typedef __attribute__((ext_vector_type(8))) short bf16x8;   // 8 bf16 = 4 VGPR
typedef __attribute__((ext_vector_type(4))) float f32x4;

__device__ __forceinline__ float sigf(float x) { return 1.0f / (1.0f + __expf(-x)); }
__device__ __forceinline__ float tanhfast(float x) {
    float e = __expf(2.0f * x);
    return 1.0f - 2.0f / (e + 1.0f);
}
__device__ __forceinline__ unsigned short bfrn(float x) {   // fp32 -> bf16 rne
    unsigned int u = __float_as_uint(x);
    u += 0x7FFFu + ((u >> 16) & 1u);
    return (unsigned short)(u >> 16);
}
__device__ __forceinline__ float bf2f(unsigned short h) {
    return __uint_as_float(((unsigned int)h) << 16);
}

#define FMA4(A, X, W) \
    A = fmaf((X).x, (W).x, A); A = fmaf((X).y, (W).y, A); \
    A = fmaf((X).z, (W).z, A); A = fmaf((X).w, (W).w, A);

// ---------------------------------------------------------------------------
// Precomputed attention tables (position-independent, built by prep kernel).
// ---------------------------------------------------------------------------
__device__ float G_d[640];
__device__ float D_d[576];
__device__ float Wvf_d[640];
__device__ float Ce_d[576];

// ---------------------------------------------------------------------------
// prep: blocks 0..47 build MFMA weight fragments; blocks 48..52 attn tables.
// ---------------------------------------------------------------------------
__global__ __launch_bounds__(512) void prep_all(
    const float* __restrict__ Wih, const float* __restrict__ Whh,
    bf16x8* __restrict__ whF, bf16x8* __restrict__ wiF,
    const float* __restrict__ Wf, const float* __restrict__ bf,
    const float* __restrict__ Wq, const float* __restrict__ bq,
    const float* __restrict__ Wv)
{
    int id = blockIdx.x * 512 + threadIdx.x;
    if (id < 24576) {
        const float* src;
        bf16x8* dst;
        int p;
        if (id < 16384) {
            int l = id & 63, frag = id >> 6;        // 0..255
            p = frag & 1;
            int kc = (frag >> 1) & 3, ti = (frag >> 3) & 3, w = frag >> 5;
            int n  = (w + 8 * ti) * 16 + (l & 15);
            int k0 = kc * 32 + (l >> 4) * 8;
            src = &Whh[n * 128 + k0];
            dst = &whF[frag * 64 + l];
        } else {
            int id2 = id - 16384;
            int l = id2 & 63, frag = id2 >> 6;      // 0..127
            p = frag & 1;
            int kc = (frag >> 1) & 1, tile = frag >> 2;
            int n  = tile * 16 + (l & 15);
            int k0 = kc * 32 + (l >> 4) * 8;
            src = &Wih[n * 64 + k0];
            dst = &wiF[frag * 64 + l];
        }
        bf16x8 v;
        #pragma unroll
        for (int j = 0; j < 8; ++j) {
            float x = src[j];
            unsigned short hi = bfrn(x);
            unsigned short r  = p ? bfrn(x - bf2f(hi)) : hi;
            v[j] = (short)r;
        }
        *dst = v;
        return;
    }
    int i = id - 24576;
    if (i >= 2432) return;
    if (i < 640) {                       // G[n][k]
        int n = i / 10, k = i % 10;
        float s = 0.f;
        #pragma unroll 8
        for (int j = 0; j < 64; ++j) s = fmaf(Wq[n * 64 + j], Wf[j * 19 + k], s);
        G_d[i] = s;
    } else if (i < 1216) {               // D[e][n]
        int i2 = i - 640;
        int e = i2 >> 6, n = i2 & 63;
        float s = bq[n];
        #pragma unroll 8
        for (int j = 0; j < 64; ++j)
            s = fmaf(Wf[j * 19 + 10 + e] + bf[j], Wq[n * 64 + j], s);
        D_d[i2] = s;
    } else if (i < 1856) {               // Wvf[o][k]
        int i3 = i - 1216;
        int o = i3 / 10, k = i3 % 10;
        float s = 0.f;
        #pragma unroll 8
        for (int j = 0; j < 64; ++j) s = fmaf(Wv[o * 64 + j], Wf[j * 19 + k], s);
        Wvf_d[i3] = s;
    } else {                             // Ce[o][e]
        int i4 = i - 1856;
        int o = i4 / 9, e = i4 % 9;
        float s = 0.f;
        #pragma unroll 8
        for (int j = 0; j < 64; ++j)
            s = fmaf(Wf[j * 19 + 10 + e] + bf[j], Wv[o * 64 + j], s);
        Ce_d[i4] = s;
    }
}

// ---------------------------------------------------------------------------
// Kernel A v2: algebraically-collapsed attention (unchanged; ~120 us).
// ---------------------------------------------------------------------------
__global__ __launch_bounds__(64, 4) void edge_attn_ctx(
    const float* __restrict__ seqs,   // [BS,SEQ,3,3,6]
    const float* __restrict__ ets,    // [BS,SEQ,3,3,4]
    const int*   __restrict__ masks,  // [BS,SEQ,3,3]
    const float* __restrict__ Wk, const float* __restrict__ bk,
    const float* __restrict__ bv,
    float* __restrict__ ctx)          // [BS,SEQ,64]
{
    const int o   = threadIdx.x;
    const int h_o = o >> 4;
    const int lg  = (o < 40) ? o : 0;     // g/rbar lanes: (gh, gk)
    const int gh  = lg / 10, gk = lg % 10;
    const int la  = (o < 36) ? o : 0;     // att lanes: (ah, ae), l = ah*9+ae
    const int ah  = la / 9,  ae = la % 9;

    const float* wkp = &Wk[o * 6];
    const float wk0 = wkp[0], wk1 = wkp[1], wk2 = wkp[2],
                wk3 = wkp[3], wk4 = wkp[4], wk5 = wkp[5];
    const float bkr = bk[o];

    float Greg[16], Dreg[16];
    #pragma unroll
    for (int d = 0; d < 16; ++d) Greg[d] = G_d[(gh * 16 + d) * 10 + gk];
    #pragma unroll
    for (int d = 0; d < 16; ++d) Dreg[d] = D_d[ae * 64 + ah * 16 + d];
    float Wvfr[10];
    #pragma unroll
    for (int k = 0; k < 10; ++k) Wvfr[k] = Wvf_d[o * 10 + k];
    const float bvr = bv[o];
    float Cer[9];
    #pragma unroll
    for (int e = 0; e < 9; ++e) Cer[e] = Ce_d[o * 9 + e] + bvr;

    __shared__ float s_seq[54], s_et[36], s_key[64], s_g[40];
    __shared__ float s_att[36], s_exp[36], s_rbar[40];
    __shared__ int   s_mask[9];

    float r_seq = 0.f, r_et = 0.f; int r_mask = 0;
    {
        int p0 = blockIdx.x;
        if (o < 54) r_seq  = seqs[p0 * 54 + o];
        if (o < 36) r_et   = ets[p0 * 36 + o];
        if (o < 9)  r_mask = masks[p0 * 9 + o];
    }

    for (int p = blockIdx.x; p < NPOS; p += gridDim.x) {
        if (o < 54) s_seq[o]  = r_seq;
        if (o < 36) s_et[o]   = r_et;
        if (o < 9)  s_mask[o] = r_mask;
        __syncthreads();

        {
            int pn = p + gridDim.x;
            if (pn < NPOS) {
                if (o < 54) r_seq  = seqs[pn * 54 + o];
                if (o < 36) r_et   = ets[pn * 36 + o];
                if (o < 9)  r_mask = masks[pn * 9 + o];
            }
        }
        float key = bkr;
        key = fmaf(s_seq[24], wk0, key);
        key = fmaf(s_seq[25], wk1, key);
        key = fmaf(s_seq[26], wk2, key);
        key = fmaf(s_seq[27], wk3, key);
        key = fmaf(s_seq[28], wk4, key);
        key = fmaf(s_seq[29], wk5, key);
        s_key[o] = key;
        __syncthreads();

        float tt = 0.f;
        if (o < 40) {
            float g = 0.f;
            #pragma unroll
            for (int d = 0; d < 16; ++d) g = fmaf(Greg[d], s_key[gh * 16 + d], g);
            s_g[o] = g;
        }
        if (o < 36) {
            #pragma unroll
            for (int d = 0; d < 16; ++d) tt = fmaf(Dreg[d], s_key[ah * 16 + d], tt);
        }
        __syncthreads();

        float a = 0.f;
        if (o < 36) {
            a = tt;
            #pragma unroll
            for (int k = 0; k < 6; ++k) a = fmaf(s_seq[ae * 6 + k], s_g[ah * 10 + k], a);
            #pragma unroll
            for (int k = 0; k < 4; ++k) a = fmaf(s_et[ae * 4 + k], s_g[ah * 10 + 6 + k], a);
            a *= 0.25f;
            if (s_mask[ae] == 0) a = -1.0e10f;
            s_att[o] = a;
        }
        __syncthreads();

        float ex = 0.f;
        if (o < 36) {
            float mx = s_att[ah * 9 + 0];
            #pragma unroll
            for (int e = 1; e < 9; ++e) mx = fmaxf(mx, s_att[ah * 9 + e]);
            ex = __expf(a - mx);
            s_exp[o] = ex;
        }
        __syncthreads();

        if (o < 40) {
            float rb = 0.f;
            #pragma unroll
            for (int e = 0; e < 9; ++e) {
                float x = (gk < 6) ? s_seq[e * 6 + gk] : s_et[e * 4 + (gk - 6)];
                rb = fmaf(s_exp[gh * 9 + e], x, rb);
            }
            s_rbar[o] = rb;
        }
        __syncthreads();

        {
            float ssum = 0.f;
            #pragma unroll
            for (int e = 0; e < 9; ++e) ssum += s_exp[h_o * 9 + e];
            float acc = 0.f;
            #pragma unroll
            for (int k = 0; k < 10; ++k) acc = fmaf(s_rbar[h_o * 10 + k], Wvfr[k], acc);
            #pragma unroll
            for (int e = 0; e < 9; ++e) acc = fmaf(s_exp[h_o * 9 + e], Cer[e], acc);
            ctx[p * 64 + o] = acc * (1.0f / ssum);
        }
    }
}

// ---------------------------------------------------------------------------
// Kernel C v12: pair-step MFMA LSTM.
//  - x(2u) in tile rows 0-7, x(2u+1) in rows 8-15: ONE junk-free x-pass per
//    2 steps (24 MFMAs, was 48). 60 MFMAs/step avg (was 72).
//  - h parity planes: L (rows 0-7 real, 8-15 zero) holds odd h; H (rows 8-15
//    real) holds even h. h-pass A-fragment zeros steer each step's
//    contribution into only its own acc rows; acc carries gx(s1) across the
//    even step untouched.
//  - permlane pointwise: one shfl_xor(32) pair per acc chain redistributes
//    rows so EVERY lane owns 2 real unit-rows (lq0:{0,1} lq1:{4,5} lq2:{2,3}
//    lq3:{6,7}) -> transcendental work halves (was 4 rows, half junk).
//  - 1 barrier/step (unchanged); ctx prefetched one pair ahead.
// ---------------------------------------------------------------------------
#define MFMA16(A, B, C) __builtin_amdgcn_mfma_f32_16x16x32_bf16(A, B, C, 0, 0, 0)
#define MM4(F, W0, W1, W2, W3) \
    a0 = MFMA16(F, W0, a0); a1 = MFMA16(F, W1, a1); \
    a2 = MFMA16(F, W2, a2); a3 = MFMA16(F, W3, a3);

#define HPASS \
    MM4(hfh[0], whr[0][0][0], whr[1][0][0], whr[2][0][0], whr[3][0][0]) \
    MM4(hfh[1], whr[0][1][0], whr[1][1][0], whr[2][1][0], whr[3][1][0]) \
    MM4(hfh[2], whr[0][2][0], whr[1][2][0], whr[2][2][0], whr[3][2][0]) \
    MM4(hfh[3], whr[0][3][0], whr[1][3][0], whr[2][3][0], whr[3][3][0]) \
    MM4(hfl[0], whr[0][0][0], whr[1][0][0], whr[2][0][0], whr[3][0][0]) \
    MM4(hfl[1], whr[0][1][0], whr[1][1][0], whr[2][1][0], whr[3][1][0]) \
    MM4(hfl[2], whr[0][2][0], whr[1][2][0], whr[2][2][0], whr[3][2][0]) \
    MM4(hfl[3], whr[0][3][0], whr[1][3][0], whr[2][3][0], whr[3][3][0]) \
    MM4(hfh[0], whr[0][0][1], whr[1][0][1], whr[2][0][1], whr[3][0][1]) \
    MM4(hfh[1], whr[0][1][1], whr[1][1][1], whr[2][1][1], whr[3][1][1]) \
    MM4(hfh[2], whr[0][2][1], whr[1][2][1], whr[2][2][1], whr[3][2][1]) \
    MM4(hfh[3], whr[0][3][1], whr[1][3][1], whr[2][3][1], whr[3][3][1])

// redistribute acc rows -> (g0,g1) = this lane's 2 unit-rows, per parity
#define REDIST_E(ch, g0, g1) { \
    float s2_ = __shfl_xor(ch[2], 32), s3_ = __shfl_xor(ch[3], 32); \
    g0 = lolq ? ch[0] : s2_;  g1 = lolq ? ch[1] : s3_; }
#define REDIST_O(ch, g0, g1) { \
    float s0_ = __shfl_xor(ch[0], 32), s1_ = __shfl_xor(ch[1], 32); \
    g0 = lolq ? s0_ : ch[2];  g1 = lolq ? s1_ : ch[3]; }

#define PWBODY(gi0,gf0,gg0,go0,gi1,gf1,gg1,go1, WB0, WB1) { \
    float i0_ = sigf(gi0 + bi), f0_ = sigf(gf0 + bff); \
    float gA_ = tanhfast(gg0 + bg), o0_ = sigf(go0 + bo); \
    c20 = fmaf(f0_, c20, i0_ * gA_); \
    float hv0_ = o0_ * tanhfast(c20); \
    float i1_ = sigf(gi1 + bi), f1_ = sigf(gf1 + bff); \
    float gB_ = tanhfast(gg1 + bg), o1_ = sigf(go1 + bo); \
    c21 = fmaf(f1_, c21, i1_ * gB_); \
    float hv1_ = o1_ * tanhfast(c21); \
    unsigned short hh0_ = bfrn(hv0_), hh1_ = bfrn(hv1_); \
    unsigned short hl0_ = bfrn(hv0_ - bf2f(hh0_)), hl1_ = bfrn(hv1_ - bf2f(hh1_)); \
    *(unsigned short*)((char*)s_hh + (WB0)) = hh0_; \
    *(unsigned short*)((char*)s_hl + (WB0)) = hl0_; \
    *(unsigned short*)((char*)s_hh + (WB1)) = hh1_; \
    *(unsigned short*)((char*)s_hl + (WB1)) = hl1_; }

__global__ __launch_bounds__(512, 2) void lstm_mfma(
    const float*  __restrict__ ctx,    // [BS,SEQ,64]
    const bf16x8* __restrict__ whF,    // 16384 frags
    const bf16x8* __restrict__ wiFg,   // 8192 frags
    const float*  __restrict__ b_ih, const float* __restrict__ b_hh,
    const float*  __restrict__ W_out, const float* __restrict__ b_out,
    float* __restrict__ out)           // [BS,64]
{
    const int t  = threadIdx.x;
    const int w  = t >> 6, l = t & 63;
    const int lm = l & 15, lq = l >> 4;
    const int row0 = blockIdx.x * 8;            // 8 real rows per block

    __shared__ bf16x8 s_wi[8192];                       // 128 KB  W_ih frags
    __shared__ unsigned short s_xh[1024], s_xl[1024];   // [16][64] pair tile
    __shared__ unsigned short s_hh[4096], s_hl[4096];   // planes L(0B) H(4096B)

    for (int i = t; i < 8192; i += 512) s_wi[i] = wiFg[i];
    for (int i = t; i < 1024; i += 512) { s_xh[i] = 0; s_xl[i] = 0; }
    for (int i = t; i < 4096; i += 512) { s_hh[i] = 0; s_hl[i] = 0; }

    // W_hh fragments (hi+lo) -> registers for the whole loop
    bf16x8 whr[4][4][2];
    #pragma unroll
    for (int ti = 0; ti < 4; ++ti)
        #pragma unroll
        for (int kc = 0; kc < 4; ++kc)
            #pragma unroll
            for (int p = 0; p < 2; ++p)
                whr[ti][kc][p] = whF[(((w * 4 + ti) * 4 + kc) * 2 + p) * 64 + l];

    const int m = w * 16 + lm;
    const float bi  = b_ih[m]       + b_hh[m];
    const float bff = b_ih[128 + m] + b_hh[128 + m];
    const float bg  = b_ih[256 + m] + b_hh[256 + m];
    const float bo  = b_ih[384 + m] + b_hh[384 + m];

    // lane owns batch rows urb, urb+1 (xor32-reachable for both parities)
    const int  urb  = ((lq & 1) << 2) | (lq & 2);
    const bool lolq = (lq < 2);
    float c20 = 0.f, c21 = 0.f;

    const int xrow  = t >> 5;                  // 0..15 (all real now)
    const int xl32  = t & 31;
    const int srow  = xrow & 7;                // batch row
    const int spair = xrow >> 3;               // step-in-pair
    const float2* ctx2 = (const float2*)ctx;
    const int xbase = (row0 + srow) * SEQ + spair;
    const int xwb   = xrow * 128 + ((4 * xl32) ^ ((xrow & 7) << 4));
    const int swzr  = (lm & 7) << 4;
    const int hwb_m = 32 * w + 2 * lm;
    // h-write bytes: even -> plane H rows 8+b; odd -> plane L rows b
    const int wb0e = 4096 + (8 + urb) * 256 + (hwb_m ^ (urb << 4));
    const int wb1e = 4096 + (9 + urb) * 256 + (hwb_m ^ ((urb + 1) << 4));
    const int wb0o = urb * 256 + (hwb_m ^ (urb << 4));
    const int wb1o = (urb + 1) * 256 + (hwb_m ^ ((urb + 1) << 4));

    // prefetch pair 0
    float2 xv = ctx2[xbase * 32 + xl32];

    for (int u = 0; u < SEQ / 2; ++u) {
        // ================= EVEN step s0 = 2u =================
        {   // stage x-pair (rows 0-7 = x(s0), rows 8-15 = x(s1))
            unsigned short xh0 = bfrn(xv.x), xh1 = bfrn(xv.y);
            unsigned short xl0 = bfrn(xv.x - bf2f(xh0)), xl1 = bfrn(xv.y - bf2f(xh1));
            *(unsigned int*)((char*)s_xh + xwb) = (unsigned int)xh0 | ((unsigned int)xh1 << 16);
            *(unsigned int*)((char*)s_xl + xwb) = (unsigned int)xl0 | ((unsigned int)xl1 << 16);
        }
        __syncthreads();   // x-pair + h(s0-1) (plane L) visible

        float2 xvn = make_float2(0.f, 0.f);
        if (u + 1 < SEQ / 2) xvn = ctx2[(xbase + 2 * u + 2) * 32 + xl32];

        bf16x8 hfh[4], hfl[4];
        if (u > 0) {
            #pragma unroll
            for (int kc = 0; kc < 4; ++kc) {
                int b = lm * 256 + ((kc * 64 + lq * 16) ^ swzr);   // plane L
                hfh[kc] = *(const bf16x8*)((const char*)s_hh + b);
                hfl[kc] = *(const bf16x8*)((const char*)s_hl + b);
            }
        }
        bf16x8 xfh[2], xfl[2];
        #pragma unroll
        for (int kc = 0; kc < 2; ++kc) {
            int b = lm * 128 + ((kc * 64 + lq * 16) ^ swzr);
            xfh[kc] = *(const bf16x8*)((const char*)s_xh + b);
            xfl[kc] = *(const bf16x8*)((const char*)s_xl + b);
        }

        f32x4 a0 = {0.f,0.f,0.f,0.f}, a1 = a0, a2 = a0, a3 = a0;

        if (u > 0) { HPASS }           // h(s0-1)W -> acc rows 0-7 only

        #pragma unroll                  // x-pass: both steps, junk-free
        for (int kc = 0; kc < 2; ++kc) {
            bf16x8 wihi[4], wilo[4];
            #pragma unroll
            for (int ti = 0; ti < 4; ++ti) {
                int base = (((w + 8 * ti) * 2 + kc) * 2) * 64 + l;
                wihi[ti] = s_wi[base];
                wilo[ti] = s_wi[base + 64];
            }
            MM4(xfh[kc], wihi[0], wihi[1], wihi[2], wihi[3])
            MM4(xfl[kc], wihi[0], wihi[1], wihi[2], wihi[3])
            MM4(xfh[kc], wilo[0], wilo[1], wilo[2], wilo[3])
        }

        {   // even pointwise: rows 0-7 (sources in lq01 r*, xor32 for lq23)
            float gi0, gi1, gf0, gf1, gg0, gg1, go0, go1;
            REDIST_E(a0, gi0, gi1)
            REDIST_E(a1, gf0, gf1)
            REDIST_E(a2, gg0, gg1)
            REDIST_E(a3, go0, go1)
            PWBODY(gi0, gf0, gg0, go0, gi1, gf1, gg1, go1, wb0e, wb1e)
        }

        // ================= ODD step s1 = 2u+1 =================
        __syncthreads();   // h(s0) (plane H) visible
        #pragma unroll
        for (int kc = 0; kc < 4; ++kc) {
            int b = 4096 + lm * 256 + ((kc * 64 + lq * 16) ^ swzr);  // plane H
            hfh[kc] = *(const bf16x8*)((const char*)s_hh + b);
            hfl[kc] = *(const bf16x8*)((const char*)s_hl + b);
        }
        HPASS                          // h(s0)W -> acc rows 8-15 only

        {   // odd pointwise: rows 8-15 (sources in lq23 r*, xor32 for lq01)
            float gi0, gi1, gf0, gf1, gg0, gg1, go0, go1;
            REDIST_O(a0, gi0, gi1)
            REDIST_O(a1, gf0, gf1)
            REDIST_O(a2, gg0, gg1)
            REDIST_O(a3, go0, go1)
            PWBODY(gi0, gf0, gg0, go0, gi1, gf1, gg1, go1, wb0o, wb1o)
        }
        xv = xvn;
    }
    __syncthreads();

    // ---- epilogue: h(SEQ-1)=h(49) is odd -> plane L rows 0-7 ----
    {
        const int row = t >> 5;
        if (row < 8) {
            const int j0 = t & 31, j1 = (t & 31) + 32;
            const int rswz = (row & 7) << 4;
            float accA = b_out[j0], accB = b_out[j1];
            #pragma unroll
            for (int kq = 0; kq < 16; ++kq) {
                int b = row * 256 + ((kq * 16) ^ rswz);
                bf16x8 hh8 = *(const bf16x8*)((const char*)s_hh + b);
                bf16x8 hl8 = *(const bf16x8*)((const char*)s_hl + b);
                #pragma unroll
                for (int e = 0; e < 8; ++e) {
                    float h = bf2f((unsigned short)hh8[e]) + bf2f((unsigned short)hl8[e]);
                    int k = kq * 8 + e;
                    accA = fmaf(h, W_out[j0 * 128 + k], accA);
                    accB = fmaf(h, W_out[j1 * 128 + k], accB);
                }
            }
            out[(row0 + row) * 64 + j0] = accA;
            out[(row0 + row) * 64 + j1] = accB;
        }
    }
}

// ---------------------------------------------------------------------------
extern "C" void kernel_launch(void* const* d_in, const int* in_sizes, int n_in,
                              void* d_out, int out_size, void* d_ws, size_t ws_size,
                              hipStream_t stream) {
    (void)in_sizes; (void)n_in; (void)out_size; (void)ws_size;
    const float* seqs  = (const float*)d_in[0];
    const float* ets   = (const float*)d_in[1];
    const int*   masks = (const int*)d_in[2];
    const float* Wf  = (const float*)d_in[3];
    const float* bf  = (const float*)d_in[4];
    const float* Wk  = (const float*)d_in[5];
    const float* bk  = (const float*)d_in[6];
    const float* Wq  = (const float*)d_in[7];
    const float* bq  = (const float*)d_in[8];
    const float* Wv  = (const float*)d_in[9];
    const float* bv  = (const float*)d_in[10];
    const float* Wih = (const float*)d_in[11];
    const float* Whh = (const float*)d_in[12];
    const float* bih = (const float*)d_in[13];
    const float* bhh = (const float*)d_in[14];
    const float* Wo  = (const float*)d_in[15];
    const float* bo  = (const float*)d_in[16];

    // ws layout: whF 256K | wiF 128K | ctx 26.2M  (attn tables in device globals)
    char* ws = (char*)d_ws;
    bf16x8* whF = (bf16x8*)(ws);
    bf16x8* wiF = (bf16x8*)(ws + 262144);
    float*  ctx = (float*) (ws + 262144 + 131072);

    hipLaunchKernelGGL(prep_all, dim3(53), dim3(512), 0, stream,
                       Wih, Whh, whF, wiF, Wf, bf, Wq, bq, Wv);
    hipLaunchKernelGGL(edge_attn_ctx, dim3(4096), dim3(64), 0, stream,
                       seqs, ets, masks, Wk, bk, bv, ctx);
    hipLaunchKernelGGL(lstm_mfma, dim3(256), dim3(512), 0, stream,
                       ctx, whF, wiF, bih, bhh, Wo, bo, (float*)d_out);
}